// Round 7
// baseline (4487.741 us; speedup 1.0000x reference)
//
#include <hip/hip_runtime.h>
#include <stdint.h>

#define HID 512
#define IND 256
#define OUTD 256
#define BROWS 64

typedef __attribute__((ext_vector_type(8))) short short8;   // 8 bf16
typedef __attribute__((ext_vector_type(4))) short short4v;  // 4 bf16
typedef __attribute__((ext_vector_type(4))) float f32x4;

#define MFMA16(a,b,c) __builtin_amdgcn_mfma_f32_16x16x32_bf16(a,b,c,0,0,0)

__device__ __forceinline__ short f2bf(float f){
  uint32_t u = __builtin_bit_cast(uint32_t, f);
  u += 0x7FFFu + ((u>>16)&1u);
  return (short)(u>>16);
}
__device__ __forceinline__ float bf2f(short s){
  uint32_t u = ((uint32_t)(uint16_t)s) << 16;
  return __builtin_bit_cast(float, u);
}
// pack one f32 as (hi bf16 | lo bf16) in one u32; unpack = hi + lo
__device__ __forceinline__ int pack_hl(float v){
  short hi = f2bf(v);
  short lo = f2bf(v - bf2f(hi));
  return (((int)(uint16_t)hi) << 16) | (int)(uint16_t)lo;
}
__device__ __forceinline__ float unpk(int p){
  float vh = __builtin_bit_cast(float, (uint32_t)p & 0xFFFF0000u);
  float vl = __builtin_bit_cast(float, (uint32_t)p << 16);
  return vh + vl;
}
// AGPR cold storage (gfx950 unified file: arch VGPRs are capped at 64 for
// 1024-thr blocks; the other 64 are AGPRs the allocator won't use for
// ordinary values -> park step-invariant state there explicitly).
__device__ __forceinline__ int to_agpr(int v){
  int a;
  asm("v_accvgpr_write_b32 %0, %1" : "=a"(a) : "v"(v));
  return a;
}
__device__ __forceinline__ int from_agpr(int a){
  int v;
  asm("v_accvgpr_read_b32 %0, %1" : "=v"(v) : "a"(a));
  return v;
}
__device__ __forceinline__ float tanh_fast(float x){
  float e = __builtin_amdgcn_exp2f(x * 2.88539008177792681472f);
  return __builtin_fmaf(-2.0f, __builtin_amdgcn_rcpf(e + 1.0f), 1.0f);
}
__device__ __forceinline__ float neigh(float v){
  // lane^1 exchange via DPP quad_perm [1,0,3,2]
  return __builtin_bit_cast(float,
      __builtin_amdgcn_mov_dpp(__builtin_bit_cast(int, v), 0xB1, 0xF, 0xF, true));
}
__device__ __forceinline__ uint32_t axor(uint32_t b){ return b ^ (((b>>7)&7u)<<4); }

// ---------------- sigma: one power-iteration step, one block per matrix ----------------
__global__ void sigma_kernel(const float* __restrict__ lw, const float* __restrict__ lu,
                             const float* __restrict__ ow, const float* __restrict__ ou,
                             float* __restrict__ invs)
{
  __shared__ float sv[HID];
  __shared__ float red[8];
  const int g = threadIdx.x;  // 512 threads
  const int m = blockIdx.x;   // 0..3
  const float* W = (m < 3) ? (lw + (size_t)m*HID*HID) : ow;
  const float* u = (m < 3) ? (lu + m*HID) : ou;
  float t1 = 0.f;
  for (int k = 0; k < HID; ++k) t1 += W[(size_t)k*HID + g] * u[k];
  float ss = t1*t1;
  #pragma unroll
  for (int d = 32; d; d >>= 1) ss += __shfl_xor(ss, d);
  if ((g & 63) == 0) red[g >> 6] = ss;
  __syncthreads();
  float tot = 0.f;
  #pragma unroll
  for (int i = 0; i < 8; ++i) tot += red[i];
  float nrm = sqrtf(tot);
  sv[g] = t1 / (nrm + 1e-12f);
  __syncthreads();
  float n = 0.f;
  const float* Wr = W + (size_t)g*HID;
  for (int k = 0; k < HID; ++k) n += Wr[k] * sv[k];
  float ss2 = n*n;
  #pragma unroll
  for (int d = 32; d; d >>= 1) ss2 += __shfl_xor(ss2, d);
  if ((g & 63) == 0) red[g >> 6] = ss2;
  __syncthreads();
  float tot2 = 0.f;
  #pragma unroll
  for (int i = 0; i < 8; ++i) tot2 += red[i];
  float nn = sqrtf(tot2);
  float sigma = tot2 / (nn + 1e-12f);   // dot(u2, Wv)
  if (g == 0) invs[m] = 1.0f / sigma;
}

// ---------------- weight packing: INTERLEAVED hi/lo, MFMA-frag-sequential ----------------
// Frag f = kt*NCT + ctg occupies 2 KiB: [0,1K) hi halves, [1K,2K) lo halves.
// Within: halfword (lane*8 + j). B-frag mapping: lane l holds
// B[k = kt*32 + (l>>4)*8 + j][col = ctg*16 + (l&15)].
__global__ void pack_wsum_il(const float* __restrict__ lw, const float* __restrict__ invs,
                             short* __restrict__ pw)
{
  int i = blockIdx.x*blockDim.x + threadIdx.x;   // < 512*512
  int j = i & 7, lane = (i >> 3) & 63, f = i >> 9;
  int kt = f >> 5, ctg = f & 31;                 // NCT = 32
  int k = kt*32 + (lane >> 4)*8 + j;
  int g = ctg*16 + (lane & 15);
  size_t idx = (size_t)g*HID + k;
  float v = lw[idx]*invs[0] + lw[262144 + idx]*invs[1] + lw[524288 + idx]*invs[2];
  short hi = f2bf(v);
  pw[(size_t)f*1024 + lane*8 + j]       = hi;
  pw[(size_t)f*1024 + 512 + lane*8 + j] = f2bf(v - bf2f(hi));
}

template<int K, int N>
__global__ void pack_b_il(const float* __restrict__ W, short* __restrict__ pc)
{
  int i = blockIdx.x*blockDim.x + threadIdx.x;   // < K*N
  int j = i & 7, lane = (i >> 3) & 63, f = i >> 9;
  constexpr int NCT = N/16;
  int kt = f / NCT, ctg = f % NCT;
  int k = kt*32 + (lane >> 4)*8 + j;
  int c = ctg*16 + (lane & 15);
  float v = W[(size_t)c*K + k];
  short hi = f2bf(v);
  pc[(size_t)f*1024 + lane*8 + j]       = hi;
  pc[(size_t)f*1024 + 512 + lane*8 + j] = f2bf(v - bf2f(hi));
}

template<int K, int N>
__global__ void pack_b_hi(const float* __restrict__ W, short* __restrict__ pb)
{
  int i = blockIdx.x*blockDim.x + threadIdx.x;   // < K*N
  int j = i & 7, lane = (i >> 3) & 63, f = i >> 9;
  constexpr int NCT = N/16;
  int kt = f / NCT, ctg = f % NCT;
  int k = kt*32 + (lane >> 4)*8 + j;
  int c = ctg*16 + (lane & 15);
  pb[i] = f2bf(W[(size_t)c*K + k]);
}

__global__ void pack_small(const float* __restrict__ lb, const float* __restrict__ ow,
                           const float* __restrict__ invs,
                           float* __restrict__ bsum, float* __restrict__ cs, float* __restrict__ cn)
{
  int g = blockIdx.x*blockDim.x + threadIdx.x;
  if (g >= HID) return;
  bsum[g] = lb[g] + lb[HID + g] + lb[2*HID + g];
  float is = invs[3];
  cs[g] = ow[(size_t)g*HID + g] * is;        // osc_sn[g][g]
  cn[g] = ow[(size_t)g*HID + (g^1)] * is;    // osc_sn[g][g^1]
}

// ---------------- fused main: 64 rows, 1024 threads (16 waves), 128-reg budget ----------------
// Arch VGPRs: h 32 + frags <=24 + ptrs/consts ~20 ~= 78.  AGPRs: xp 32 + acc 16 = 48.
// Total ~126 <= 128 cap -> zero spills by construction.
__global__ void __launch_bounds__(1024) fused_main(
    const float* __restrict__ x,
    const float* __restrict__ winb,
    const float* __restrict__ headb,
    const int*  __restrict__ stepsp,
    const short* __restrict__ packWC,   // Wsum interleaved hi/lo, 1 MiB
    const short* __restrict__ packIC,   // W_in interleaved hi/lo, 512 KiB
    const short* __restrict__ packHd,   // head hi only, 256 KiB
    const float* __restrict__ bsumA,
    const float* __restrict__ csA,
    const float* __restrict__ cnA,
    float* __restrict__ out)
{
  extern __shared__ char lds[];     // 128 KiB: [A_hi 64K][A_lo 64K], frag-major
  char* ldsHi = lds;
  char* ldsLo = lds + 65536;
  const int tid  = threadIdx.x;
  const int lane = tid & 63;
  const int l15  = lane & 15;
  const int ql   = lane >> 4;       // 0..3
  const int wid  = tid >> 6;        // 0..15
  const int wr   = wid >> 3;        // 0..1  (row half: 32 rows)
  const int wc   = wid & 7;         // 0..7  (col group: 64 cols)
  const int rb   = blockIdx.x;

  // ---- stage x tile -> LDS bf16 hi/lo, frag-major [rtg 0..3][kt 0..7] ----
  {
    const float* xb = x + (size_t)rb*BROWS*IND;
    #pragma unroll
    for (int i = 0; i < 4; ++i) {
      int fi  = i*1024 + tid;       // 4096 float4s
      int row = fi >> 6;            // 0..63
      int c   = (fi & 63)*4;        // 0..252
      f32x4 v = *(const f32x4*)(xb + (size_t)row*IND + c);
      short4v hi4, lo4;
      #pragma unroll
      for (int j = 0; j < 4; ++j) {
        short h16 = f2bf(v[j]);
        hi4[j] = h16;
        lo4[j] = f2bf(v[j] - bf2f(h16));
      }
      int rtg = row >> 4, kt = c >> 5, qd = (c >> 3) & 3;
      uint32_t byte = (uint32_t)(((rtg*8 + kt)*1024) + (qd*16 + (row & 15))*16 + (c & 7)*2);
      *(short4v*)(ldsHi + axor(byte)) = hi4;
      *(short4v*)(ldsLo + axor(byte)) = lo4;
    }
  }
  __syncthreads();

  const int nsteps = stepsp[0];

  // Oscillator: uniform 2x2 rotation blocks -> one (cs, cn) pair per lane parity.
  const float cs_s = csA[wc*64 + l15];
  const float cn_s = cnA[wc*64 + l15];

  // ---- x_emb = x @ W_in^T + W_in_b + b_sum  (3-pass split precision) ----
  f32x4 xe[2][4];
  #pragma unroll
  for (int ct = 0; ct < 4; ++ct) {
    int c = wc*64 + ct*16 + l15;
    float s = winb[c] + bsumA[c];
    #pragma unroll
    for (int rt = 0; rt < 2; ++rt) {
      f32x4 z; z[0]=s; z[1]=s; z[2]=s; z[3]=s;
      xe[rt][ct] = z;
    }
  }
  {
    const char* pI = (const char*)packIC + (size_t)wc*8192 + (size_t)lane*16;
    for (int kt = 0; kt < 8; ++kt) {
      short8 ah[2], al[2];
      #pragma unroll
      for (int rt = 0; rt < 2; ++rt) {
        uint32_t byte = axor((uint32_t)(((wr*2 + rt)*8 + kt)*1024 + lane*16));
        ah[rt] = *(const short8*)(ldsHi + byte);
        al[rt] = *(const short8*)(ldsLo + byte);
      }
      #pragma unroll
      for (int ct = 0; ct < 4; ++ct) {
        short8 bh = *(const short8*)(pI + ct*2048);
        short8 bl = *(const short8*)(pI + ct*2048 + 1024);
        #pragma unroll
        for (int rt = 0; rt < 2; ++rt) {
          xe[rt][ct] = MFMA16(ah[rt], bh, xe[rt][ct]);
          xe[rt][ct] = MFMA16(al[rt], bh, xe[rt][ct]);
          xe[rt][ct] = MFMA16(ah[rt], bl, xe[rt][ct]);
        }
      }
      pI += 65536;
    }
  }
  __syncthreads();

  // ---- h init + park packed xe in AGPRs ----
  f32x4 h[2][4];
  int xpa[2][4][4];       // AGPR-resident (static indexing only)
  #pragma unroll
  for (int rt = 0; rt < 2; ++rt)
    #pragma unroll
    for (int ct = 0; ct < 4; ++ct)
      #pragma unroll
      for (int r = 0; r < 4; ++r) {
        float v = xe[rt][ct][r];
        h[rt][ct][r] = (nsteps >= 1) ? 0.5f * tanh_fast(v) : 0.f;
        xpa[rt][ct][r] = to_agpr(pack_hl(v));
      }

  const char* baseW = (const char*)packWC + (size_t)wc*8192 + (size_t)lane*16;

  // ---- recurrence steps 2..nsteps ----
  for (int s = 1; s < nsteps; ++s) {
    // t = tanh(h) -> LDS hi/lo A-tiles (this wave's 32 rows, its 64 cols as K-slices)
    #pragma unroll
    for (int rt = 0; rt < 2; ++rt) {
      uint32_t rcomp = (uint32_t)((wr*2 + rt)*16384);
      #pragma unroll
      for (int ct = 0; ct < 4; ++ct) {
        int c = wc*64 + ct*16 + l15;
        uint32_t wcomp = (uint32_t)(((c >> 5)*1024) + (((c >> 3) & 3)*256) + ((c & 7)*2) + ql*64);
        #pragma unroll
        for (int r = 0; r < 4; ++r) {
          float t = tanh_fast(h[rt][ct][r]);
          short hi16 = f2bf(t);
          uint32_t byte = axor(rcomp + wcomp + (uint32_t)(r*16));
          *(short*)(ldsHi + byte) = hi16;
          *(short*)(ldsLo + byte) = f2bf(t - bf2f(hi16));
        }
      }
    }
    __syncthreads();

    #pragma unroll
    for (int ch = 0; ch < 2; ++ch) {      // ct-halves: acc only 16 regs live (AGPR)
      f32x4 acc[2][2];
      #pragma unroll
      for (int rt = 0; rt < 2; ++rt)
        #pragma unroll
        for (int c2 = 0; c2 < 2; ++c2) {
          int ct = ch*2 + c2;
          #pragma unroll
          for (int r = 0; r < 4; ++r) {
            float hv = h[rt][ct][r];
            acc[rt][c2][r] = __builtin_fmaf(cs_s, hv,
                               __builtin_fmaf(cn_s, neigh(hv),
                                 unpk(from_agpr(xpa[rt][ct][r]))));
          }
        }
      const char* p = baseW + ch*4096;
      #pragma unroll 1
      for (int kt = 0; kt < 16; ++kt) {
        short8 bh0 = *(const short8*)(p);
        short8 bl0 = *(const short8*)(p + 1024);
        short8 bh1 = *(const short8*)(p + 2048);
        short8 bl1 = *(const short8*)(p + 3072);
        #pragma unroll
        for (int rt = 0; rt < 2; ++rt) {
          uint32_t byte = axor((uint32_t)(((wr*2 + rt)*16 + kt)*1024 + lane*16));
          short8 ah = *(const short8*)(ldsHi + byte);
          short8 al = *(const short8*)(ldsLo + byte);
          acc[rt][0] = MFMA16(ah, bh0, acc[rt][0]);
          acc[rt][0] = MFMA16(al, bh0, acc[rt][0]);
          acc[rt][0] = MFMA16(ah, bl0, acc[rt][0]);
          acc[rt][1] = MFMA16(ah, bh1, acc[rt][1]);
          acc[rt][1] = MFMA16(al, bh1, acc[rt][1]);
          acc[rt][1] = MFMA16(ah, bl1, acc[rt][1]);
        }
        p += 65536;
      }
      #pragma unroll
      for (int rt = 0; rt < 2; ++rt)
        #pragma unroll
        for (int c2 = 0; c2 < 2; ++c2) {
          int ct = ch*2 + c2;
          #pragma unroll
          for (int r = 0; r < 4; ++r)
            h[rt][ct][r] = __builtin_fmaf(0.5f, tanh_fast(acc[rt][c2][r]), 0.5f*h[rt][ct][r]);
        }
    }
    __syncthreads();
  }

  // ---- head: out = h @ head_w^T + head_b  (A split hi/lo, W single bf16) ----
  #pragma unroll
  for (int rt = 0; rt < 2; ++rt) {
    uint32_t rcomp = (uint32_t)((wr*2 + rt)*16384);
    #pragma unroll
    for (int ct = 0; ct < 4; ++ct) {
      int c = wc*64 + ct*16 + l15;
      uint32_t wcomp = (uint32_t)(((c >> 5)*1024) + (((c >> 3) & 3)*256) + ((c & 7)*2) + ql*64);
      #pragma unroll
      for (int r = 0; r < 4; ++r) {
        float hv = h[rt][ct][r];
        short hi16 = f2bf(hv);
        uint32_t byte = axor(rcomp + wcomp + (uint32_t)(r*16));
        *(short*)(ldsHi + byte) = hi16;
        *(short*)(ldsLo + byte) = f2bf(hv - bf2f(hi16));
      }
    }
  }
  __syncthreads();

  int oc[2]; float hbv[2];
  #pragma unroll
  for (int c2 = 0; c2 < 2; ++c2) { oc[c2] = wc*32 + c2*16 + l15; hbv[c2] = headb[oc[c2]]; }
  f32x4 o[2][2];
  #pragma unroll
  for (int rt = 0; rt < 2; ++rt)
    #pragma unroll
    for (int c2 = 0; c2 < 2; ++c2) {
      f32x4 z; z[0]=hbv[c2]; z[1]=hbv[c2]; z[2]=hbv[c2]; z[3]=hbv[c2];
      o[rt][c2] = z;
    }
  {
    const char* pHd = (const char*)packHd + (size_t)wc*2048 + (size_t)lane*16;
    #pragma unroll 2
    for (int kt = 0; kt < 16; ++kt) {
      short8 ah[2], al[2];
      #pragma unroll
      for (int rt = 0; rt < 2; ++rt) {
        uint32_t byte = axor((uint32_t)(((wr*2 + rt)*16 + kt)*1024 + lane*16));
        ah[rt] = *(const short8*)(ldsHi + byte);
        al[rt] = *(const short8*)(ldsLo + byte);
      }
      #pragma unroll
      for (int c2 = 0; c2 < 2; ++c2) {
        short8 b = *(const short8*)(pHd + c2*1024);
        #pragma unroll
        for (int rt = 0; rt < 2; ++rt) {
          o[rt][c2] = MFMA16(ah[rt], b, o[rt][c2]);
          o[rt][c2] = MFMA16(al[rt], b, o[rt][c2]);
        }
      }
      pHd += 16384;
    }
  }
  const size_t rowg = (size_t)rb*BROWS + wr*32;
  #pragma unroll
  for (int rt = 0; rt < 2; ++rt)
    #pragma unroll
    for (int c2 = 0; c2 < 2; ++c2)
      #pragma unroll
      for (int r = 0; r < 4; ++r) {
        size_t row = rowg + rt*16 + ql*4 + r;
        out[row*OUTD + oc[c2]] = o[rt][c2][r];
      }
}

extern "C" void kernel_launch(void* const* d_in, const int* in_sizes, int n_in,
                              void* d_out, int out_size, void* d_ws, size_t ws_size,
                              hipStream_t stream)
{
  const float* x    = (const float*)d_in[0];
  const float* winw = (const float*)d_in[1];
  const float* winb = (const float*)d_in[2];
  const float* lw   = (const float*)d_in[3];
  const float* lb   = (const float*)d_in[4];
  const float* lu   = (const float*)d_in[5];
  const float* ow   = (const float*)d_in[6];
  const float* ou   = (const float*)d_in[7];
  const float* hw   = (const float*)d_in[8];
  const float* hb   = (const float*)d_in[9];
  const int*   st   = (const int*)d_in[10];
  float* out = (float*)d_out;
  char*  ws  = (char*)d_ws;

  float* invs   = (float*)(ws);
  float* bsum   = (float*)(ws + 1024);
  float* cs     = (float*)(ws + 4096);
  float* cn     = (float*)(ws + 8192);
  short* packWC = (short*)(ws + 16384);                 // 1 MiB (interleaved hi/lo)
  short* packIC = (short*)(ws + 16384 + 1048576);       // 512 KiB (interleaved hi/lo)
  short* packHd = (short*)(ws + 16384 + 1048576 + 524288); // 256 KiB (hi only)

  sigma_kernel<<<4, 512, 0, stream>>>(lw, lu, ow, ou, invs);
  pack_wsum_il<<<1024, 256, 0, stream>>>(lw, invs, packWC);
  pack_b_il<256, 512><<<512, 256, 0, stream>>>(winw, packIC);
  pack_b_hi<512, 256><<<512, 256, 0, stream>>>(hw, packHd);
  pack_small<<<2, 256, 0, stream>>>(lb, ow, invs, bsum, cs, cn);

  hipFuncSetAttribute((const void*)fused_main,
                      hipFuncAttributeMaxDynamicSharedMemorySize, 131072);
  fused_main<<<65536/BROWS, 1024, 131072, stream>>>(x, winb, hb, st,
                                                    packWC, packIC, packHd,
                                                    bsum, cs, cn, out);
}

// Round 8
// 4296.362 us; speedup vs baseline: 1.0445x; 1.0445x over previous
//
#include <hip/hip_runtime.h>
#include <stdint.h>

#define HID 512
#define IND 256
#define OUTD 256
#define BROWS 64

typedef __attribute__((ext_vector_type(8))) short short8;   // 8 bf16 (4 VGPRs)
typedef __attribute__((ext_vector_type(4))) short short4v;  // 4 bf16
typedef __attribute__((ext_vector_type(4))) float f32x4;

#define MFMA16(a,b,c) __builtin_amdgcn_mfma_f32_16x16x32_bf16(a,b,c,0,0,0)

__device__ __forceinline__ short f2bf(float f){
  uint32_t u = __builtin_bit_cast(uint32_t, f);
  u += 0x7FFFu + ((u>>16)&1u);
  return (short)(u>>16);
}
__device__ __forceinline__ float bf2f(short s){
  uint32_t u = ((uint32_t)(uint16_t)s) << 16;
  return __builtin_bit_cast(float, u);
}
// pack one f32 as (hi bf16 | lo bf16) in one u32; unpack = hi + lo
__device__ __forceinline__ int pack_hl(float v){
  short hi = f2bf(v);
  short lo = f2bf(v - bf2f(hi));
  return (((int)(uint16_t)hi) << 16) | (int)(uint16_t)lo;
}
__device__ __forceinline__ float unpk(int p){
  float vh = __builtin_bit_cast(float, (uint32_t)p & 0xFFFF0000u);
  float vl = __builtin_bit_cast(float, (uint32_t)p << 16);
  return vh + vl;
}
// Explicit accum-half storage. gfx950 splits the unified RF 50/50 arch/accum
// when MFMA is present; arch overflow spills to SCRATCH (not to idle AGPRs),
// so step-invariant state is parked in AGPRs by hand.
__device__ __forceinline__ int to_agpr(int v){
  int a;
  asm("v_accvgpr_write_b32 %0, %1" : "=a"(a) : "v"(v));
  return a;
}
__device__ __forceinline__ int from_agpr(int a){
  int v;
  asm("v_accvgpr_read_b32 %0, %1" : "=v"(v) : "a"(a));
  return v;
}
__device__ __forceinline__ float tanh_fast(float x){
  float e = __builtin_amdgcn_exp2f(x * 2.88539008177792681472f);
  return __builtin_fmaf(-2.0f, __builtin_amdgcn_rcpf(e + 1.0f), 1.0f);
}
__device__ __forceinline__ float neigh(float v){
  // lane^1 exchange via DPP quad_perm [1,0,3,2]
  return __builtin_bit_cast(float,
      __builtin_amdgcn_mov_dpp(__builtin_bit_cast(int, v), 0xB1, 0xF, 0xF, true));
}
__device__ __forceinline__ uint32_t axor(uint32_t b){ return b ^ (((b>>7)&7u)<<4); }

// ---------------- sigma: one power-iteration step, one block per matrix ----------------
__global__ void sigma_kernel(const float* __restrict__ lw, const float* __restrict__ lu,
                             const float* __restrict__ ow, const float* __restrict__ ou,
                             float* __restrict__ invs)
{
  __shared__ float sv[HID];
  __shared__ float red[8];
  const int g = threadIdx.x;  // 512 threads
  const int m = blockIdx.x;   // 0..3
  const float* W = (m < 3) ? (lw + (size_t)m*HID*HID) : ow;
  const float* u = (m < 3) ? (lu + m*HID) : ou;
  float t1 = 0.f;
  for (int k = 0; k < HID; ++k) t1 += W[(size_t)k*HID + g] * u[k];
  float ss = t1*t1;
  #pragma unroll
  for (int d = 32; d; d >>= 1) ss += __shfl_xor(ss, d);
  if ((g & 63) == 0) red[g >> 6] = ss;
  __syncthreads();
  float tot = 0.f;
  #pragma unroll
  for (int i = 0; i < 8; ++i) tot += red[i];
  float nrm = sqrtf(tot);
  sv[g] = t1 / (nrm + 1e-12f);
  __syncthreads();
  float n = 0.f;
  const float* Wr = W + (size_t)g*HID;
  for (int k = 0; k < HID; ++k) n += Wr[k] * sv[k];
  float ss2 = n*n;
  #pragma unroll
  for (int d = 32; d; d >>= 1) ss2 += __shfl_xor(ss2, d);
  if ((g & 63) == 0) red[g >> 6] = ss2;
  __syncthreads();
  float tot2 = 0.f;
  #pragma unroll
  for (int i = 0; i < 8; ++i) tot2 += red[i];
  float nn = sqrtf(tot2);
  float sigma = tot2 / (nn + 1e-12f);   // dot(u2, Wv)
  if (g == 0) invs[m] = 1.0f / sigma;
}

// ---------------- weight packing: INTERLEAVED hi/lo, MFMA-frag-sequential ----------------
// Frag f = kt*NCT + ctg occupies 2 KiB: [0,1K) hi halves, [1K,2K) lo halves.
// B-frag mapping: lane l holds B[k = kt*32 + (l>>4)*8 + j][col = ctg*16 + (l&15)].
__global__ void pack_wsum_il(const float* __restrict__ lw, const float* __restrict__ invs,
                             short* __restrict__ pw)
{
  int i = blockIdx.x*blockDim.x + threadIdx.x;   // < 512*512
  int j = i & 7, lane = (i >> 3) & 63, f = i >> 9;
  int kt = f >> 5, ctg = f & 31;                 // NCT = 32
  int k = kt*32 + (lane >> 4)*8 + j;
  int g = ctg*16 + (lane & 15);
  size_t idx = (size_t)g*HID + k;
  float v = lw[idx]*invs[0] + lw[262144 + idx]*invs[1] + lw[524288 + idx]*invs[2];
  short hi = f2bf(v);
  pw[(size_t)f*1024 + lane*8 + j]       = hi;
  pw[(size_t)f*1024 + 512 + lane*8 + j] = f2bf(v - bf2f(hi));
}

template<int K, int N>
__global__ void pack_b_il(const float* __restrict__ W, short* __restrict__ pc)
{
  int i = blockIdx.x*blockDim.x + threadIdx.x;   // < K*N
  int j = i & 7, lane = (i >> 3) & 63, f = i >> 9;
  constexpr int NCT = N/16;
  int kt = f / NCT, ctg = f % NCT;
  int k = kt*32 + (lane >> 4)*8 + j;
  int c = ctg*16 + (lane & 15);
  float v = W[(size_t)c*K + k];
  short hi = f2bf(v);
  pc[(size_t)f*1024 + lane*8 + j]       = hi;
  pc[(size_t)f*1024 + 512 + lane*8 + j] = f2bf(v - bf2f(hi));
}

template<int K, int N>
__global__ void pack_b_hi(const float* __restrict__ W, short* __restrict__ pb)
{
  int i = blockIdx.x*blockDim.x + threadIdx.x;   // < K*N
  int j = i & 7, lane = (i >> 3) & 63, f = i >> 9;
  constexpr int NCT = N/16;
  int kt = f / NCT, ctg = f % NCT;
  int k = kt*32 + (lane >> 4)*8 + j;
  int c = ctg*16 + (lane & 15);
  pb[i] = f2bf(W[(size_t)c*K + k]);
}

__global__ void pack_small(const float* __restrict__ lb, const float* __restrict__ ow,
                           const float* __restrict__ invs,
                           float* __restrict__ bsum, float* __restrict__ cs, float* __restrict__ cn)
{
  int g = blockIdx.x*blockDim.x + threadIdx.x;
  if (g >= HID) return;
  bsum[g] = lb[g] + lb[HID + g] + lb[2*HID + g];
  float is = invs[3];
  cs[g] = ow[(size_t)g*HID + g] * is;        // osc_sn[g][g]
  cn[g] = ow[(size_t)g*HID + (g^1)] * is;    // osc_sn[g][g^1]
}

// ---------------- fused main: 64 rows, 512 threads (8 waves), wave tile 64x64 ----------------
// STATIC 128 KiB LDS (visible to the allocator -> 1 block/CU -> 2 waves/SIMD
// -> 256-reg unified budget, split 128 arch + 128 accum).
// Arch half: h 64 + transient frags <=24 + ptrs/consts ~20  ~= 108 <= 128.
// Accum half: xp 64 (explicit AGPR) + MFMA acc 32            ~=  96 <= 128.
__global__ void __launch_bounds__(512) fused_main(
    const float* __restrict__ x,
    const float* __restrict__ winb,
    const float* __restrict__ headb,
    const int*  __restrict__ stepsp,
    const short* __restrict__ packWC,   // Wsum interleaved hi/lo, 1 MiB
    const short* __restrict__ packIC,   // W_in interleaved hi/lo, 512 KiB
    const short* __restrict__ packHd,   // head hi only, 256 KiB
    const float* __restrict__ bsumA,
    const float* __restrict__ csA,
    const float* __restrict__ cnA,
    float* __restrict__ out)
{
  __shared__ char ldsbuf[131072];   // [A_hi 64K][A_lo 64K], frag-major
  char* ldsHi = ldsbuf;
  char* ldsLo = ldsbuf + 65536;
  const int tid  = threadIdx.x;
  const int lane = tid & 63;
  const int l15  = lane & 15;
  const int ql   = lane >> 4;       // 0..3
  const int wc   = tid >> 6;        // 0..7 (col group: 64 cols); every wave covers rows 0..63
  const int rb   = blockIdx.x;

  // ---- stage x tile -> LDS bf16 hi/lo, frag-major [rtg 0..3][kt 0..7] ----
  {
    const float* xb = x + (size_t)rb*BROWS*IND;
    #pragma unroll
    for (int i = 0; i < 8; ++i) {
      int fi  = i*512 + tid;        // 4096 float4s
      int row = fi >> 6;            // 0..63
      int c   = (fi & 63)*4;        // 0..252
      f32x4 v = *(const f32x4*)(xb + (size_t)row*IND + c);
      short4v hi4, lo4;
      #pragma unroll
      for (int j = 0; j < 4; ++j) {
        short h16 = f2bf(v[j]);
        hi4[j] = h16;
        lo4[j] = f2bf(v[j] - bf2f(h16));
      }
      int rtg = row >> 4, kt = c >> 5, qd = (c >> 3) & 3;
      uint32_t byte = (uint32_t)(((rtg*8 + kt)*1024) + (qd*16 + (row & 15))*16 + (c & 7)*2);
      *(short4v*)(ldsHi + axor(byte)) = hi4;
      *(short4v*)(ldsLo + axor(byte)) = lo4;
    }
  }
  __syncthreads();

  const int nsteps = stepsp[0];

  // Oscillator: uniform 2x2 rotation blocks -> one (cs, cn) pair per lane.
  const float cs_s = csA[wc*64 + l15];
  const float cn_s = cnA[wc*64 + l15];

  // ---- x_emb = x @ W_in^T + W_in_b + b_sum  (3-pass split precision) ----
  f32x4 xe[4][4];
  #pragma unroll
  for (int ct = 0; ct < 4; ++ct) {
    int c = wc*64 + ct*16 + l15;
    float s = winb[c] + bsumA[c];
    #pragma unroll
    for (int rt = 0; rt < 4; ++rt) {
      f32x4 z; z[0]=s; z[1]=s; z[2]=s; z[3]=s;
      xe[rt][ct] = z;
    }
  }
  {
    const char* pI = (const char*)packIC + (size_t)wc*8192 + (size_t)lane*16;
    for (int kt = 0; kt < 8; ++kt) {
      #pragma unroll
      for (int rt = 0; rt < 4; ++rt) {
        uint32_t byte = axor((uint32_t)((rt*8 + kt)*1024 + lane*16));
        short8 ah = *(const short8*)(ldsHi + byte);
        short8 al = *(const short8*)(ldsLo + byte);
        #pragma unroll
        for (int ct = 0; ct < 4; ++ct) {
          short8 bh = *(const short8*)(pI + ct*2048);
          short8 bl = *(const short8*)(pI + ct*2048 + 1024);
          xe[rt][ct] = MFMA16(ah, bh, xe[rt][ct]);
          xe[rt][ct] = MFMA16(al, bh, xe[rt][ct]);
          xe[rt][ct] = MFMA16(ah, bl, xe[rt][ct]);
        }
      }
      pI += 65536;
    }
  }
  __syncthreads();

  // ---- h init + park packed xe in the accum half ----
  f32x4 h[4][4];
  int xpa[4][4][4];       // AGPR-resident (static indexing, fully unrolled)
  #pragma unroll
  for (int rt = 0; rt < 4; ++rt)
    #pragma unroll
    for (int ct = 0; ct < 4; ++ct)
      #pragma unroll
      for (int r = 0; r < 4; ++r) {
        float v = xe[rt][ct][r];
        h[rt][ct][r] = (nsteps >= 1) ? 0.5f * tanh_fast(v) : 0.f;
        xpa[rt][ct][r] = to_agpr(pack_hl(v));
      }

  const char* baseW = (const char*)packWC + (size_t)wc*8192 + (size_t)lane*16;

  // ---- recurrence steps 2..nsteps ----
  for (int s = 1; s < nsteps; ++s) {
    // t = tanh(h) -> LDS hi/lo A-tiles
    #pragma unroll
    for (int rt = 0; rt < 4; ++rt) {
      uint32_t rcomp = (uint32_t)(rt*16384);
      #pragma unroll
      for (int ct = 0; ct < 4; ++ct) {
        int c = wc*64 + ct*16 + l15;
        uint32_t wcomp = (uint32_t)(((c >> 5)*1024) + (((c >> 3) & 3)*256) + ((c & 7)*2) + ql*64);
        #pragma unroll
        for (int r = 0; r < 4; ++r) {
          float t = tanh_fast(h[rt][ct][r]);
          short hi16 = f2bf(t);
          uint32_t byte = axor(rcomp + wcomp + (uint32_t)(r*16));
          *(short*)(ldsHi + byte) = hi16;
          *(short*)(ldsLo + byte) = f2bf(t - bf2f(hi16));
        }
      }
    }
    __syncthreads();

    #pragma unroll
    for (int ch = 0; ch < 2; ++ch) {      // ct-halves: acc 32 regs live (accum half)
      f32x4 acc[4][2];
      #pragma unroll
      for (int rt = 0; rt < 4; ++rt)
        #pragma unroll
        for (int c2 = 0; c2 < 2; ++c2) {
          int ct = ch*2 + c2;
          #pragma unroll
          for (int r = 0; r < 4; ++r) {
            float hv = h[rt][ct][r];
            acc[rt][c2][r] = __builtin_fmaf(cs_s, hv,
                               __builtin_fmaf(cn_s, neigh(hv),
                                 unpk(from_agpr(xpa[rt][ct][r]))));
          }
        }
      const char* p = baseW + ch*4096;
      #pragma unroll 1
      for (int kt = 0; kt < 16; ++kt) {
        short8 bh0 = *(const short8*)(p);
        short8 bl0 = *(const short8*)(p + 1024);
        short8 bh1 = *(const short8*)(p + 2048);
        short8 bl1 = *(const short8*)(p + 3072);
        #pragma unroll
        for (int rt = 0; rt < 4; ++rt) {
          uint32_t byte = axor((uint32_t)((rt*16 + kt)*1024 + lane*16));
          short8 ah = *(const short8*)(ldsHi + byte);
          short8 al = *(const short8*)(ldsLo + byte);
          acc[rt][0] = MFMA16(ah, bh0, acc[rt][0]);
          acc[rt][0] = MFMA16(al, bh0, acc[rt][0]);
          acc[rt][0] = MFMA16(ah, bl0, acc[rt][0]);
          acc[rt][1] = MFMA16(ah, bh1, acc[rt][1]);
          acc[rt][1] = MFMA16(al, bh1, acc[rt][1]);
          acc[rt][1] = MFMA16(ah, bl1, acc[rt][1]);
        }
        p += 65536;
      }
      #pragma unroll
      for (int rt = 0; rt < 4; ++rt)
        #pragma unroll
        for (int c2 = 0; c2 < 2; ++c2) {
          int ct = ch*2 + c2;
          #pragma unroll
          for (int r = 0; r < 4; ++r)
            h[rt][ct][r] = __builtin_fmaf(0.5f, tanh_fast(acc[rt][c2][r]), 0.5f*h[rt][ct][r]);
        }
    }
    __syncthreads();
  }

  // ---- head: out = h @ head_w^T + head_b  (A split hi/lo, W single bf16) ----
  #pragma unroll
  for (int rt = 0; rt < 4; ++rt) {
    uint32_t rcomp = (uint32_t)(rt*16384);
    #pragma unroll
    for (int ct = 0; ct < 4; ++ct) {
      int c = wc*64 + ct*16 + l15;
      uint32_t wcomp = (uint32_t)(((c >> 5)*1024) + (((c >> 3) & 3)*256) + ((c & 7)*2) + ql*64);
      #pragma unroll
      for (int r = 0; r < 4; ++r) {
        float hv = h[rt][ct][r];
        short hi16 = f2bf(hv);
        uint32_t byte = axor(rcomp + wcomp + (uint32_t)(r*16));
        *(short*)(ldsHi + byte) = hi16;
        *(short*)(ldsLo + byte) = f2bf(hv - bf2f(hi16));
      }
    }
  }
  __syncthreads();

  int oc[2]; float hbv[2];
  #pragma unroll
  for (int c2 = 0; c2 < 2; ++c2) { oc[c2] = wc*32 + c2*16 + l15; hbv[c2] = headb[oc[c2]]; }
  f32x4 o[4][2];
  #pragma unroll
  for (int rt = 0; rt < 4; ++rt)
    #pragma unroll
    for (int c2 = 0; c2 < 2; ++c2) {
      f32x4 z; z[0]=hbv[c2]; z[1]=hbv[c2]; z[2]=hbv[c2]; z[3]=hbv[c2];
      o[rt][c2] = z;
    }
  {
    const char* pHd = (const char*)packHd + (size_t)wc*2048 + (size_t)lane*16;
    #pragma unroll 1
    for (int kt = 0; kt < 16; ++kt) {
      #pragma unroll
      for (int rt = 0; rt < 4; ++rt) {
        uint32_t byte = axor((uint32_t)((rt*16 + kt)*1024 + lane*16));
        short8 ah = *(const short8*)(ldsHi + byte);
        short8 al = *(const short8*)(ldsLo + byte);
        #pragma unroll
        for (int c2 = 0; c2 < 2; ++c2) {
          short8 b = *(const short8*)(pHd + c2*1024);
          o[rt][c2] = MFMA16(ah, b, o[rt][c2]);
          o[rt][c2] = MFMA16(al, b, o[rt][c2]);
        }
      }
      pHd += 16384;
    }
  }
  const size_t rowg = (size_t)rb*BROWS;
  #pragma unroll
  for (int rt = 0; rt < 4; ++rt)
    #pragma unroll
    for (int c2 = 0; c2 < 2; ++c2)
      #pragma unroll
      for (int r = 0; r < 4; ++r) {
        size_t row = rowg + rt*16 + ql*4 + r;
        out[row*OUTD + oc[c2]] = o[rt][c2][r];
      }
}

extern "C" void kernel_launch(void* const* d_in, const int* in_sizes, int n_in,
                              void* d_out, int out_size, void* d_ws, size_t ws_size,
                              hipStream_t stream)
{
  const float* x    = (const float*)d_in[0];
  const float* winw = (const float*)d_in[1];
  const float* winb = (const float*)d_in[2];
  const float* lw   = (const float*)d_in[3];
  const float* lb   = (const float*)d_in[4];
  const float* lu   = (const float*)d_in[5];
  const float* ow   = (const float*)d_in[6];
  const float* ou   = (const float*)d_in[7];
  const float* hw   = (const float*)d_in[8];
  const float* hb   = (const float*)d_in[9];
  const int*   st   = (const int*)d_in[10];
  float* out = (float*)d_out;
  char*  ws  = (char*)d_ws;

  float* invs   = (float*)(ws);
  float* bsum   = (float*)(ws + 1024);
  float* cs     = (float*)(ws + 4096);
  float* cn     = (float*)(ws + 8192);
  short* packWC = (short*)(ws + 16384);                    // 1 MiB (interleaved hi/lo)
  short* packIC = (short*)(ws + 16384 + 1048576);          // 512 KiB (interleaved hi/lo)
  short* packHd = (short*)(ws + 16384 + 1048576 + 524288); // 256 KiB (hi only)

  sigma_kernel<<<4, 512, 0, stream>>>(lw, lu, ow, ou, invs);
  pack_wsum_il<<<1024, 256, 0, stream>>>(lw, invs, packWC);
  pack_b_il<256, 512><<<512, 256, 0, stream>>>(winw, packIC);
  pack_b_hi<512, 256><<<512, 256, 0, stream>>>(hw, packHd);
  pack_small<<<2, 256, 0, stream>>>(lb, ow, invs, bsum, cs, cn);

  fused_main<<<65536/BROWS, 512, 0, stream>>>(x, winb, hb, st,
                                              packWC, packIC, packHd,
                                              bsum, cs, cn, out);
}

// Round 9
// 3146.574 us; speedup vs baseline: 1.4262x; 1.3654x over previous
//
#include <hip/hip_runtime.h>
#include <stdint.h>

#define HID 512
#define IND 256
#define OUTD 256
#define BROWS 32

typedef __attribute__((ext_vector_type(8))) short short8;   // 8 bf16 (4 VGPRs)
typedef __attribute__((ext_vector_type(4))) short short4v;  // 4 bf16
typedef __attribute__((ext_vector_type(4))) float f32x4;
typedef __attribute__((ext_vector_type(4))) int   i32x4;

#define MFMA16(a,b,c) __builtin_amdgcn_mfma_f32_16x16x32_bf16(a,b,c,0,0,0)

__device__ __forceinline__ short f2bf(float f){
  uint32_t u = __builtin_bit_cast(uint32_t, f);
  u += 0x7FFFu + ((u>>16)&1u);
  return (short)(u>>16);
}
__device__ __forceinline__ float bf2f(short s){
  uint32_t u = ((uint32_t)(uint16_t)s) << 16;
  return __builtin_bit_cast(float, u);
}
// pack one f32 as (hi bf16 | lo bf16) in one u32; unpack = hi + lo
__device__ __forceinline__ int pack_hl(float v){
  short hi = f2bf(v);
  short lo = f2bf(v - bf2f(hi));
  return (((int)(uint16_t)hi) << 16) | (int)(uint16_t)lo;
}
__device__ __forceinline__ float unpk(int p){
  float vh = __builtin_bit_cast(float, (uint32_t)p & 0xFFFF0000u);
  float vl = __builtin_bit_cast(float, (uint32_t)p << 16);
  return vh + vl;
}
__device__ __forceinline__ float tanh_fast(float x){
  float e = __builtin_amdgcn_exp2f(x * 2.88539008177792681472f);
  return __builtin_fmaf(-2.0f, __builtin_amdgcn_rcpf(e + 1.0f), 1.0f);
}
__device__ __forceinline__ float neigh(float v){
  // lane^1 exchange via DPP quad_perm [1,0,3,2]
  return __builtin_bit_cast(float,
      __builtin_amdgcn_mov_dpp(__builtin_bit_cast(int, v), 0xB1, 0xF, 0xF, true));
}
__device__ __forceinline__ uint32_t axor(uint32_t b){ return b ^ (((b>>7)&7u)<<4); }

// ---------------- sigma: one power-iteration step, one block per matrix ----------------
__global__ void sigma_kernel(const float* __restrict__ lw, const float* __restrict__ lu,
                             const float* __restrict__ ow, const float* __restrict__ ou,
                             float* __restrict__ invs)
{
  __shared__ float sv[HID];
  __shared__ float red[8];
  const int g = threadIdx.x;  // 512 threads
  const int m = blockIdx.x;   // 0..3
  const float* W = (m < 3) ? (lw + (size_t)m*HID*HID) : ow;
  const float* u = (m < 3) ? (lu + m*HID) : ou;
  float t1 = 0.f;
  for (int k = 0; k < HID; ++k) t1 += W[(size_t)k*HID + g] * u[k];
  float ss = t1*t1;
  #pragma unroll
  for (int d = 32; d; d >>= 1) ss += __shfl_xor(ss, d);
  if ((g & 63) == 0) red[g >> 6] = ss;
  __syncthreads();
  float tot = 0.f;
  #pragma unroll
  for (int i = 0; i < 8; ++i) tot += red[i];
  float nrm = sqrtf(tot);
  sv[g] = t1 / (nrm + 1e-12f);
  __syncthreads();
  float n = 0.f;
  const float* Wr = W + (size_t)g*HID;
  for (int k = 0; k < HID; ++k) n += Wr[k] * sv[k];
  float ss2 = n*n;
  #pragma unroll
  for (int d = 32; d; d >>= 1) ss2 += __shfl_xor(ss2, d);
  if ((g & 63) == 0) red[g >> 6] = ss2;
  __syncthreads();
  float tot2 = 0.f;
  #pragma unroll
  for (int i = 0; i < 8; ++i) tot2 += red[i];
  float nn = sqrtf(tot2);
  float sigma = tot2 / (nn + 1e-12f);   // dot(u2, Wv)
  if (g == 0) invs[m] = 1.0f / sigma;
}

// ---------------- weight packing: INTERLEAVED hi/lo, MFMA-frag-sequential ----------------
// Frag f = kt*NCT + ctg occupies 2 KiB: [0,1K) hi halves, [1K,2K) lo halves.
// B-frag mapping: lane l holds B[k = kt*32 + (l>>4)*8 + j][col = ctg*16 + (l&15)].
__global__ void pack_wsum_il(const float* __restrict__ lw, const float* __restrict__ invs,
                             short* __restrict__ pw)
{
  int i = blockIdx.x*blockDim.x + threadIdx.x;   // < 512*512
  int j = i & 7, lane = (i >> 3) & 63, f = i >> 9;
  int kt = f >> 5, ctg = f & 31;                 // NCT = 32
  int k = kt*32 + (lane >> 4)*8 + j;
  int g = ctg*16 + (lane & 15);
  size_t idx = (size_t)g*HID + k;
  float v = lw[idx]*invs[0] + lw[262144 + idx]*invs[1] + lw[524288 + idx]*invs[2];
  short hi = f2bf(v);
  pw[(size_t)f*1024 + lane*8 + j]       = hi;
  pw[(size_t)f*1024 + 512 + lane*8 + j] = f2bf(v - bf2f(hi));
}

template<int K, int N>
__global__ void pack_b_il(const float* __restrict__ W, short* __restrict__ pc)
{
  int i = blockIdx.x*blockDim.x + threadIdx.x;   // < K*N
  int j = i & 7, lane = (i >> 3) & 63, f = i >> 9;
  constexpr int NCT = N/16;
  int kt = f / NCT, ctg = f % NCT;
  int k = kt*32 + (lane >> 4)*8 + j;
  int c = ctg*16 + (lane & 15);
  float v = W[(size_t)c*K + k];
  short hi = f2bf(v);
  pc[(size_t)f*1024 + lane*8 + j]       = hi;
  pc[(size_t)f*1024 + 512 + lane*8 + j] = f2bf(v - bf2f(hi));
}

template<int K, int N>
__global__ void pack_b_hi(const float* __restrict__ W, short* __restrict__ pb)
{
  int i = blockIdx.x*blockDim.x + threadIdx.x;   // < K*N
  int j = i & 7, lane = (i >> 3) & 63, f = i >> 9;
  constexpr int NCT = N/16;
  int kt = f / NCT, ctg = f % NCT;
  int k = kt*32 + (lane >> 4)*8 + j;
  int c = ctg*16 + (lane & 15);
  pb[i] = f2bf(W[(size_t)c*K + k]);
}

__global__ void pack_small(const float* __restrict__ lb, const float* __restrict__ ow,
                           const float* __restrict__ invs,
                           float* __restrict__ bsum, float* __restrict__ cs, float* __restrict__ cn)
{
  int g = blockIdx.x*blockDim.x + threadIdx.x;
  if (g >= HID) return;
  bsum[g] = lb[g] + lb[HID + g] + lb[2*HID + g];
  float is = invs[3];
  cs[g] = ow[(size_t)g*HID + g] * is;        // osc_sn[g][g]
  cn[g] = ow[(size_t)g*HID + (g^1)] * is;    // osc_sn[g][g^1]
}

// ---------------- fused main: 32 rows, 512 threads (8 waves), wave tile 32x64 ----------------
// xe lives in LDS (packed hi|lo u32), NOT in registers. Per-thread state:
// arch: h 32 + frags <=24 + ptrs/consts ~30  ~= 90 << 128   (no spill possible)
// accum: MFMA acc 16                          ~= 16 << 128
// LDS 128 KiB static: [A_hi 32K][A_lo 32K][xe 64K] -> 1 block/CU, 2 waves/SIMD.
__global__ void __launch_bounds__(512) fused_main(
    const float* __restrict__ x,
    const float* __restrict__ winb,
    const float* __restrict__ headb,
    const int*  __restrict__ stepsp,
    const short* __restrict__ packWC,   // Wsum interleaved hi/lo, 1 MiB
    const short* __restrict__ packIC,   // W_in interleaved hi/lo, 512 KiB
    const short* __restrict__ packHd,   // head hi only, 256 KiB
    const float* __restrict__ bsumA,
    const float* __restrict__ csA,
    const float* __restrict__ cnA,
    float* __restrict__ out)
{
  __shared__ char ldsbuf[131072];
  char* ldsHi = ldsbuf;             // 32 KiB A_hi (frag-major, 32 frags x 1 KiB)
  char* ldsLo = ldsbuf + 32768;     // 32 KiB A_lo
  char* ldsXe = ldsbuf + 65536;     // 64 KiB xe: [wave][ch][chunk] x 1 KiB lane-linear
  const int tid  = threadIdx.x;
  const int lane = tid & 63;
  const int l15  = lane & 15;
  const int ql   = lane >> 4;       // 0..3
  const int wid  = tid >> 6;        // 0..7
  const int wc   = wid;             // col group: 64 cols; every wave covers rows 0..31
  const int rb   = blockIdx.x;

  // ---- stage x tile -> LDS bf16 hi/lo, frag-major [rtg 0..1][kt 0..7] ----
  {
    const float* xb = x + (size_t)rb*BROWS*IND;
    #pragma unroll
    for (int i = 0; i < 4; ++i) {
      int fi  = i*512 + tid;        // 2048 float4s
      int row = fi >> 6;            // 0..31
      int c   = (fi & 63)*4;        // 0..252
      f32x4 v = *(const f32x4*)(xb + (size_t)row*IND + c);
      short4v hi4, lo4;
      #pragma unroll
      for (int j = 0; j < 4; ++j) {
        short h16 = f2bf(v[j]);
        hi4[j] = h16;
        lo4[j] = f2bf(v[j] - bf2f(h16));
      }
      int rtg = row >> 4, kt = c >> 5, qd = (c >> 3) & 3;
      uint32_t byte = (uint32_t)(((rtg*8 + kt)*1024) + (qd*16 + (row & 15))*16 + (c & 7)*2);
      *(short4v*)(ldsHi + axor(byte)) = hi4;
      *(short4v*)(ldsLo + axor(byte)) = lo4;
    }
  }
  __syncthreads();

  const int nsteps = stepsp[0];

  // Oscillator: uniform 2x2 rotation blocks -> one (cs, cn) pair per lane.
  const float cs_s = csA[wc*64 + l15];
  const float cn_s = cnA[wc*64 + l15];

  // ---- x_emb = x @ W_in^T + W_in_b + b_sum  (3-pass split precision) ----
  f32x4 xe[2][4];
  #pragma unroll
  for (int ct = 0; ct < 4; ++ct) {
    int c = wc*64 + ct*16 + l15;
    float s = winb[c] + bsumA[c];
    #pragma unroll
    for (int rt = 0; rt < 2; ++rt) {
      f32x4 z; z[0]=s; z[1]=s; z[2]=s; z[3]=s;
      xe[rt][ct] = z;
    }
  }
  {
    const char* pI = (const char*)packIC + (size_t)wc*8192 + (size_t)lane*16;
    for (int kt = 0; kt < 8; ++kt) {
      #pragma unroll
      for (int rt = 0; rt < 2; ++rt) {
        uint32_t byte = axor((uint32_t)((rt*8 + kt)*1024 + lane*16));
        short8 ah = *(const short8*)(ldsHi + byte);
        short8 al = *(const short8*)(ldsLo + byte);
        #pragma unroll
        for (int ct = 0; ct < 4; ++ct) {
          short8 bh = *(const short8*)(pI + ct*2048);
          short8 bl = *(const short8*)(pI + ct*2048 + 1024);
          xe[rt][ct] = MFMA16(ah, bh, xe[rt][ct]);
          xe[rt][ct] = MFMA16(al, bh, xe[rt][ct]);
          xe[rt][ct] = MFMA16(ah, bl, xe[rt][ct]);
        }
      }
      pI += 65536;
    }
  }
  __syncthreads();

  // ---- h init + park packed xe in LDS (wave-chunked, lane-linear b128) ----
  // element e = rt*8 + c2*4 + r within ch-half; chunk = e>>2.
  f32x4 h[2][4];
  #pragma unroll
  for (int ch = 0; ch < 2; ++ch) {
    #pragma unroll
    for (int chunk = 0; chunk < 4; ++chunk) {
      i32x4 v;
      #pragma unroll
      for (int pos = 0; pos < 4; ++pos) {
        int e = chunk*4 + pos;
        int rt = e >> 3, c2 = (e >> 2) & 1, r = e & 3;
        int ct = ch*2 + c2;
        float xv = xe[rt][ct][r];
        v[pos] = pack_hl(xv);
        h[rt][ct][r] = (nsteps >= 1) ? 0.5f * tanh_fast(xv) : 0.f;
      }
      *(i32x4*)(ldsXe + ((wid*8 + ch*4 + chunk)*1024) + lane*16) = v;
    }
  }

  const char* baseW = (const char*)packWC + (size_t)wc*8192 + (size_t)lane*16;

  // ---- recurrence steps 2..nsteps ----
  for (int s = 1; s < nsteps; ++s) {
    // t = tanh(h) -> LDS hi/lo A-tiles (32 rows x 512 k, frag (rt*16+kt))
    #pragma unroll
    for (int rt = 0; rt < 2; ++rt) {
      uint32_t rcomp = (uint32_t)(rt*16384);
      #pragma unroll
      for (int ct = 0; ct < 4; ++ct) {
        int c = wc*64 + ct*16 + l15;
        uint32_t wcomp = (uint32_t)(((c >> 5)*1024) + (((c >> 3) & 3)*256) + ((c & 7)*2) + ql*64);
        #pragma unroll
        for (int r = 0; r < 4; ++r) {
          float t = tanh_fast(h[rt][ct][r]);
          short hi16 = f2bf(t);
          uint32_t byte = axor(rcomp + wcomp + (uint32_t)(r*16));
          *(short*)(ldsHi + byte) = hi16;
          *(short*)(ldsLo + byte) = f2bf(t - bf2f(hi16));
        }
      }
    }
    __syncthreads();

    #pragma unroll
    for (int ch = 0; ch < 2; ++ch) {      // ct-halves: acc 16 regs live
      f32x4 acc[2][2];
      #pragma unroll
      for (int chunk = 0; chunk < 4; ++chunk) {
        i32x4 v = *(const i32x4*)(ldsXe + ((wid*8 + ch*4 + chunk)*1024) + lane*16);
        #pragma unroll
        for (int pos = 0; pos < 4; ++pos) {
          int e = chunk*4 + pos;
          int rt = e >> 3, c2 = (e >> 2) & 1, r = e & 3;
          int ct = ch*2 + c2;
          float hv = h[rt][ct][r];
          acc[rt][c2][r] = __builtin_fmaf(cs_s, hv,
                             __builtin_fmaf(cn_s, neigh(hv), unpk(v[pos])));
        }
      }
      const char* p = baseW + ch*4096;
      #pragma unroll 2
      for (int kt = 0; kt < 16; ++kt) {
        short8 bh0 = *(const short8*)(p);
        short8 bl0 = *(const short8*)(p + 1024);
        short8 bh1 = *(const short8*)(p + 2048);
        short8 bl1 = *(const short8*)(p + 3072);
        #pragma unroll
        for (int rt = 0; rt < 2; ++rt) {
          uint32_t byte = axor((uint32_t)((rt*16 + kt)*1024 + lane*16));
          short8 ah = *(const short8*)(ldsHi + byte);
          short8 al = *(const short8*)(ldsLo + byte);
          acc[rt][0] = MFMA16(ah, bh0, acc[rt][0]);
          acc[rt][0] = MFMA16(al, bh0, acc[rt][0]);
          acc[rt][0] = MFMA16(ah, bl0, acc[rt][0]);
          acc[rt][1] = MFMA16(ah, bh1, acc[rt][1]);
          acc[rt][1] = MFMA16(al, bh1, acc[rt][1]);
          acc[rt][1] = MFMA16(ah, bl1, acc[rt][1]);
        }
        p += 65536;
      }
      #pragma unroll
      for (int rt = 0; rt < 2; ++rt)
        #pragma unroll
        for (int c2 = 0; c2 < 2; ++c2) {
          int ct = ch*2 + c2;
          #pragma unroll
          for (int r = 0; r < 4; ++r)
            h[rt][ct][r] = __builtin_fmaf(0.5f, tanh_fast(acc[rt][c2][r]), 0.5f*h[rt][ct][r]);
        }
    }
    __syncthreads();
  }

  // ---- head: out = h @ head_w^T + head_b  (A split hi/lo, W single bf16) ----
  #pragma unroll
  for (int rt = 0; rt < 2; ++rt) {
    uint32_t rcomp = (uint32_t)(rt*16384);
    #pragma unroll
    for (int ct = 0; ct < 4; ++ct) {
      int c = wc*64 + ct*16 + l15;
      uint32_t wcomp = (uint32_t)(((c >> 5)*1024) + (((c >> 3) & 3)*256) + ((c & 7)*2) + ql*64);
      #pragma unroll
      for (int r = 0; r < 4; ++r) {
        float hv = h[rt][ct][r];
        short hi16 = f2bf(hv);
        uint32_t byte = axor(rcomp + wcomp + (uint32_t)(r*16));
        *(short*)(ldsHi + byte) = hi16;
        *(short*)(ldsLo + byte) = f2bf(hv - bf2f(hi16));
      }
    }
  }
  __syncthreads();

  int oc[2]; float hbv[2];
  #pragma unroll
  for (int c2 = 0; c2 < 2; ++c2) { oc[c2] = wc*32 + c2*16 + l15; hbv[c2] = headb[oc[c2]]; }
  f32x4 o[2][2];
  #pragma unroll
  for (int rt = 0; rt < 2; ++rt)
    #pragma unroll
    for (int c2 = 0; c2 < 2; ++c2) {
      f32x4 z; z[0]=hbv[c2]; z[1]=hbv[c2]; z[2]=hbv[c2]; z[3]=hbv[c2];
      o[rt][c2] = z;
    }
  {
    const char* pHd = (const char*)packHd + (size_t)wc*2048 + (size_t)lane*16;
    #pragma unroll 2
    for (int kt = 0; kt < 16; ++kt) {
      #pragma unroll
      for (int rt = 0; rt < 2; ++rt) {
        uint32_t byte = axor((uint32_t)((rt*16 + kt)*1024 + lane*16));
        short8 ah = *(const short8*)(ldsHi + byte);
        short8 al = *(const short8*)(ldsLo + byte);
        #pragma unroll
        for (int c2 = 0; c2 < 2; ++c2) {
          short8 b = *(const short8*)(pHd + c2*1024);
          o[rt][c2] = MFMA16(ah, b, o[rt][c2]);
          o[rt][c2] = MFMA16(al, b, o[rt][c2]);
        }
      }
      pHd += 16384;
    }
  }
  const size_t rowg = (size_t)rb*BROWS;
  #pragma unroll
  for (int rt = 0; rt < 2; ++rt)
    #pragma unroll
    for (int c2 = 0; c2 < 2; ++c2)
      #pragma unroll
      for (int r = 0; r < 4; ++r) {
        size_t row = rowg + rt*16 + ql*4 + r;
        out[row*OUTD + oc[c2]] = o[rt][c2][r];
      }
}

extern "C" void kernel_launch(void* const* d_in, const int* in_sizes, int n_in,
                              void* d_out, int out_size, void* d_ws, size_t ws_size,
                              hipStream_t stream)
{
  const float* x    = (const float*)d_in[0];
  const float* winw = (const float*)d_in[1];
  const float* winb = (const float*)d_in[2];
  const float* lw   = (const float*)d_in[3];
  const float* lb   = (const float*)d_in[4];
  const float* lu   = (const float*)d_in[5];
  const float* ow   = (const float*)d_in[6];
  const float* ou   = (const float*)d_in[7];
  const float* hw   = (const float*)d_in[8];
  const float* hb   = (const float*)d_in[9];
  const int*   st   = (const int*)d_in[10];
  float* out = (float*)d_out;
  char*  ws  = (char*)d_ws;

  float* invs   = (float*)(ws);
  float* bsum   = (float*)(ws + 1024);
  float* cs     = (float*)(ws + 4096);
  float* cn     = (float*)(ws + 8192);
  short* packWC = (short*)(ws + 16384);                    // 1 MiB (interleaved hi/lo)
  short* packIC = (short*)(ws + 16384 + 1048576);          // 512 KiB (interleaved hi/lo)
  short* packHd = (short*)(ws + 16384 + 1048576 + 524288); // 256 KiB (hi only)

  sigma_kernel<<<4, 512, 0, stream>>>(lw, lu, ow, ou, invs);
  pack_wsum_il<<<1024, 256, 0, stream>>>(lw, invs, packWC);
  pack_b_il<256, 512><<<512, 256, 0, stream>>>(winw, packIC);
  pack_b_hi<512, 256><<<512, 256, 0, stream>>>(hw, packHd);
  pack_small<<<2, 256, 0, stream>>>(lb, ow, invs, bsum, cs, cn);

  fused_main<<<65536/BROWS, 512, 0, stream>>>(x, winb, hb, st,
                                              packWC, packIC, packHd,
                                              bsum, cs, cn, out);
}

// Round 10
// 3134.154 us; speedup vs baseline: 1.4319x; 1.0040x over previous
//
#include <hip/hip_runtime.h>
#include <stdint.h>

#define HID 512
#define IND 256
#define OUTD 256
#define BROWS 32

typedef __attribute__((ext_vector_type(8))) short short8;   // 8 bf16 (4 VGPRs)
typedef __attribute__((ext_vector_type(4))) short short4v;  // 4 bf16
typedef __attribute__((ext_vector_type(4))) float f32x4;
typedef __attribute__((ext_vector_type(4))) int   i32x4;

#define MFMA16(a,b,c) __builtin_amdgcn_mfma_f32_16x16x32_bf16(a,b,c,0,0,0)

__device__ __forceinline__ short f2bf(float f){
  uint32_t u = __builtin_bit_cast(uint32_t, f);
  u += 0x7FFFu + ((u>>16)&1u);
  return (short)(u>>16);
}
__device__ __forceinline__ float bf2f(short s){
  uint32_t u = ((uint32_t)(uint16_t)s) << 16;
  return __builtin_bit_cast(float, u);
}
// pack one f32 as (hi bf16 | lo bf16) in one u32; unpack = hi + lo
__device__ __forceinline__ int pack_hl(float v){
  short hi = f2bf(v);
  short lo = f2bf(v - bf2f(hi));
  return (((int)(uint16_t)hi) << 16) | (int)(uint16_t)lo;
}
__device__ __forceinline__ float unpk(int p){
  float vh = __builtin_bit_cast(float, (uint32_t)p & 0xFFFF0000u);
  float vl = __builtin_bit_cast(float, (uint32_t)p << 16);
  return vh + vl;
}
__device__ __forceinline__ float tanh_fast(float x){
  float e = __builtin_amdgcn_exp2f(x * 2.88539008177792681472f);
  return __builtin_fmaf(-2.0f, __builtin_amdgcn_rcpf(e + 1.0f), 1.0f);
}
__device__ __forceinline__ float neigh(float v){
  // lane^1 exchange via DPP quad_perm [1,0,3,2]
  return __builtin_bit_cast(float,
      __builtin_amdgcn_mov_dpp(__builtin_bit_cast(int, v), 0xB1, 0xF, 0xF, true));
}
__device__ __forceinline__ uint32_t axor(uint32_t b){ return b ^ (((b>>7)&7u)<<4); }

// ---------------- sigma: one power-iteration step, one block per matrix ----------------
__global__ void sigma_kernel(const float* __restrict__ lw, const float* __restrict__ lu,
                             const float* __restrict__ ow, const float* __restrict__ ou,
                             float* __restrict__ invs)
{
  __shared__ float sv[HID];
  __shared__ float red[8];
  const int g = threadIdx.x;  // 512 threads
  const int m = blockIdx.x;   // 0..3
  const float* W = (m < 3) ? (lw + (size_t)m*HID*HID) : ow;
  const float* u = (m < 3) ? (lu + m*HID) : ou;
  float t1 = 0.f;
  for (int k = 0; k < HID; ++k) t1 += W[(size_t)k*HID + g] * u[k];
  float ss = t1*t1;
  #pragma unroll
  for (int d = 32; d; d >>= 1) ss += __shfl_xor(ss, d);
  if ((g & 63) == 0) red[g >> 6] = ss;
  __syncthreads();
  float tot = 0.f;
  #pragma unroll
  for (int i = 0; i < 8; ++i) tot += red[i];
  float nrm = sqrtf(tot);
  sv[g] = t1 / (nrm + 1e-12f);
  __syncthreads();
  float n = 0.f;
  const float* Wr = W + (size_t)g*HID;
  for (int k = 0; k < HID; ++k) n += Wr[k] * sv[k];
  float ss2 = n*n;
  #pragma unroll
  for (int d = 32; d; d >>= 1) ss2 += __shfl_xor(ss2, d);
  if ((g & 63) == 0) red[g >> 6] = ss2;
  __syncthreads();
  float tot2 = 0.f;
  #pragma unroll
  for (int i = 0; i < 8; ++i) tot2 += red[i];
  float nn = sqrtf(tot2);
  float sigma = tot2 / (nn + 1e-12f);   // dot(u2, Wv)
  if (g == 0) invs[m] = 1.0f / sigma;
}

// ---------------- weight packing: INTERLEAVED hi/lo, MFMA-frag-sequential ----------------
// Frag f = kt*NCT + ctg occupies 2 KiB: [0,1K) hi halves, [1K,2K) lo halves.
// B-frag mapping: lane l holds B[k = kt*32 + (l>>4)*8 + j][col = ctg*16 + (l&15)].
__global__ void pack_wsum_il(const float* __restrict__ lw, const float* __restrict__ invs,
                             short* __restrict__ pw)
{
  int i = blockIdx.x*blockDim.x + threadIdx.x;   // < 512*512
  int j = i & 7, lane = (i >> 3) & 63, f = i >> 9;
  int kt = f >> 5, ctg = f & 31;                 // NCT = 32
  int k = kt*32 + (lane >> 4)*8 + j;
  int g = ctg*16 + (lane & 15);
  size_t idx = (size_t)g*HID + k;
  float v = lw[idx]*invs[0] + lw[262144 + idx]*invs[1] + lw[524288 + idx]*invs[2];
  short hi = f2bf(v);
  pw[(size_t)f*1024 + lane*8 + j]       = hi;
  pw[(size_t)f*1024 + 512 + lane*8 + j] = f2bf(v - bf2f(hi));
}

template<int K, int N>
__global__ void pack_b_il(const float* __restrict__ W, short* __restrict__ pc)
{
  int i = blockIdx.x*blockDim.x + threadIdx.x;   // < K*N
  int j = i & 7, lane = (i >> 3) & 63, f = i >> 9;
  constexpr int NCT = N/16;
  int kt = f / NCT, ctg = f % NCT;
  int k = kt*32 + (lane >> 4)*8 + j;
  int c = ctg*16 + (lane & 15);
  float v = W[(size_t)c*K + k];
  short hi = f2bf(v);
  pc[(size_t)f*1024 + lane*8 + j]       = hi;
  pc[(size_t)f*1024 + 512 + lane*8 + j] = f2bf(v - bf2f(hi));
}

template<int K, int N>
__global__ void pack_b_hi(const float* __restrict__ W, short* __restrict__ pb)
{
  int i = blockIdx.x*blockDim.x + threadIdx.x;   // < K*N
  int j = i & 7, lane = (i >> 3) & 63, f = i >> 9;
  constexpr int NCT = N/16;
  int kt = f / NCT, ctg = f % NCT;
  int k = kt*32 + (lane >> 4)*8 + j;
  int c = ctg*16 + (lane & 15);
  pb[i] = f2bf(W[(size_t)c*K + k]);
}

__global__ void pack_small(const float* __restrict__ lb, const float* __restrict__ ow,
                           const float* __restrict__ invs,
                           float* __restrict__ bsum, float* __restrict__ cs, float* __restrict__ cn)
{
  int g = blockIdx.x*blockDim.x + threadIdx.x;
  if (g >= HID) return;
  bsum[g] = lb[g] + lb[HID + g] + lb[2*HID + g];
  float is = invs[3];
  cs[g] = ow[(size_t)g*HID + g] * is;        // osc_sn[g][g]
  cn[g] = ow[(size_t)g*HID + (g^1)] * is;    // osc_sn[g][g^1]
}

// ---------------- fused main: 32 rows, 512 threads (8 waves), wave tile 32x64 ----------------
// LDS only 64 KiB (A hi/lo) -> 2 blocks/CU -> 4 waves/SIMD; independent blocks
// overlap their VALU/barrier phases with each other's MFMA (m114 mechanism).
// Per-wave unified regs: arch h32 + xe32(packed u32) + frags 24 + addr ~15 ~= 110,
// accum acc 16 -> ~126 <= 128/wave at 16 waves/CU. No spill, no scratch.
__global__ void __launch_bounds__(512) fused_main(
    const float* __restrict__ x,
    const float* __restrict__ winb,
    const float* __restrict__ headb,
    const int*  __restrict__ stepsp,
    const short* __restrict__ packWC,   // Wsum interleaved hi/lo, 1 MiB
    const short* __restrict__ packIC,   // W_in interleaved hi/lo, 512 KiB
    const short* __restrict__ packHd,   // head hi only, 256 KiB
    const float* __restrict__ bsumA,
    const float* __restrict__ csA,
    const float* __restrict__ cnA,
    float* __restrict__ out)
{
  __shared__ char ldsbuf[65536];
  char* ldsHi = ldsbuf;             // 32 KiB A_hi (frag-major, 32 frags x 1 KiB)
  char* ldsLo = ldsbuf + 32768;     // 32 KiB A_lo
  const int tid  = threadIdx.x;
  const int lane = tid & 63;
  const int l15  = lane & 15;
  const int ql   = lane >> 4;       // 0..3
  const int wid  = tid >> 6;        // 0..7
  const int wc   = wid;             // col group: 64 cols; every wave covers rows 0..31
  const int rb   = blockIdx.x;

  // ---- stage x tile -> LDS bf16 hi/lo, frag-major [rtg 0..1][kt 0..7] ----
  {
    const float* xb = x + (size_t)rb*BROWS*IND;
    #pragma unroll
    for (int i = 0; i < 4; ++i) {
      int fi  = i*512 + tid;        // 2048 float4s
      int row = fi >> 6;            // 0..31
      int c   = (fi & 63)*4;        // 0..252
      f32x4 v = *(const f32x4*)(xb + (size_t)row*IND + c);
      short4v hi4, lo4;
      #pragma unroll
      for (int j = 0; j < 4; ++j) {
        short h16 = f2bf(v[j]);
        hi4[j] = h16;
        lo4[j] = f2bf(v[j] - bf2f(h16));
      }
      int rtg = row >> 4, kt = c >> 5, qd = (c >> 3) & 3;
      uint32_t byte = (uint32_t)(((rtg*8 + kt)*1024) + (qd*16 + (row & 15))*16 + (c & 7)*2);
      *(short4v*)(ldsHi + axor(byte)) = hi4;
      *(short4v*)(ldsLo + axor(byte)) = lo4;
    }
  }
  __syncthreads();

  const int nsteps = stepsp[0];

  // Oscillator: uniform 2x2 rotation blocks -> one (cs, cn) pair per lane.
  const float cs_s = csA[wc*64 + l15];
  const float cn_s = cnA[wc*64 + l15];

  // ---- x_emb = x @ W_in^T + W_in_b + b_sum  (3-pass split precision) ----
  f32x4 xe[2][4];
  #pragma unroll
  for (int ct = 0; ct < 4; ++ct) {
    int c = wc*64 + ct*16 + l15;
    float s = winb[c] + bsumA[c];
    #pragma unroll
    for (int rt = 0; rt < 2; ++rt) {
      f32x4 z; z[0]=s; z[1]=s; z[2]=s; z[3]=s;
      xe[rt][ct] = z;
    }
  }
  {
    const char* pI = (const char*)packIC + (size_t)wc*8192 + (size_t)lane*16;
    for (int kt = 0; kt < 8; ++kt) {
      #pragma unroll
      for (int rt = 0; rt < 2; ++rt) {
        uint32_t byte = axor((uint32_t)((rt*8 + kt)*1024 + lane*16));
        short8 ah = *(const short8*)(ldsHi + byte);
        short8 al = *(const short8*)(ldsLo + byte);
        #pragma unroll
        for (int ct = 0; ct < 4; ++ct) {
          short8 bh = *(const short8*)(pI + ct*2048);
          short8 bl = *(const short8*)(pI + ct*2048 + 1024);
          xe[rt][ct] = MFMA16(ah, bh, xe[rt][ct]);
          xe[rt][ct] = MFMA16(al, bh, xe[rt][ct]);
          xe[rt][ct] = MFMA16(ah, bl, xe[rt][ct]);
        }
      }
      pI += 65536;
    }
  }

  // ---- h init + keep packed xe resident in ARCH registers (32 u32) ----
  f32x4 h[2][4];
  i32x4 xp[2][4];     // fully static indexing (rule #20)
  #pragma unroll
  for (int rt = 0; rt < 2; ++rt)
    #pragma unroll
    for (int ct = 0; ct < 4; ++ct)
      #pragma unroll
      for (int r = 0; r < 4; ++r) {
        float xv = xe[rt][ct][r];
        xp[rt][ct][r] = pack_hl(xv);
        h[rt][ct][r] = (nsteps >= 1) ? 0.5f * tanh_fast(xv) : 0.f;
      }
  __syncthreads();

  const char* baseW = (const char*)packWC + (size_t)wc*8192 + (size_t)lane*16;

  // ---- recurrence steps 2..nsteps ----
  for (int s = 1; s < nsteps; ++s) {
    // t = tanh(h) -> LDS hi/lo A-tiles (32 rows x 512 k, frag (rt*16+kt))
    #pragma unroll
    for (int rt = 0; rt < 2; ++rt) {
      uint32_t rcomp = (uint32_t)(rt*16384);
      #pragma unroll
      for (int ct = 0; ct < 4; ++ct) {
        int c = wc*64 + ct*16 + l15;
        uint32_t wcomp = (uint32_t)(((c >> 5)*1024) + (((c >> 3) & 3)*256) + ((c & 7)*2) + ql*64);
        #pragma unroll
        for (int r = 0; r < 4; ++r) {
          float t = tanh_fast(h[rt][ct][r]);
          short hi16 = f2bf(t);
          uint32_t byte = axor(rcomp + wcomp + (uint32_t)(r*16));
          *(short*)(ldsHi + byte) = hi16;
          *(short*)(ldsLo + byte) = f2bf(t - bf2f(hi16));
        }
      }
    }
    __syncthreads();

    #pragma unroll
    for (int ch = 0; ch < 2; ++ch) {      // ct-halves: acc 16 regs live
      f32x4 acc[2][2];
      #pragma unroll
      for (int rt = 0; rt < 2; ++rt)
        #pragma unroll
        for (int c2 = 0; c2 < 2; ++c2) {
          int ct = ch*2 + c2;
          #pragma unroll
          for (int r = 0; r < 4; ++r) {
            float hv = h[rt][ct][r];
            acc[rt][c2][r] = __builtin_fmaf(cs_s, hv,
                               __builtin_fmaf(cn_s, neigh(hv), unpk(xp[rt][ct][r])));
          }
        }
      const char* p = baseW + ch*4096;
      #pragma unroll 2
      for (int kt = 0; kt < 16; ++kt) {
        short8 bh0 = *(const short8*)(p);
        short8 bl0 = *(const short8*)(p + 1024);
        short8 bh1 = *(const short8*)(p + 2048);
        short8 bl1 = *(const short8*)(p + 3072);
        #pragma unroll
        for (int rt = 0; rt < 2; ++rt) {
          uint32_t byte = axor((uint32_t)((rt*16 + kt)*1024 + lane*16));
          short8 ah = *(const short8*)(ldsHi + byte);
          short8 al = *(const short8*)(ldsLo + byte);
          acc[rt][0] = MFMA16(ah, bh0, acc[rt][0]);
          acc[rt][0] = MFMA16(al, bh0, acc[rt][0]);
          acc[rt][0] = MFMA16(ah, bl0, acc[rt][0]);
          acc[rt][1] = MFMA16(ah, bh1, acc[rt][1]);
          acc[rt][1] = MFMA16(al, bh1, acc[rt][1]);
          acc[rt][1] = MFMA16(ah, bl1, acc[rt][1]);
        }
        p += 65536;
      }
      #pragma unroll
      for (int rt = 0; rt < 2; ++rt)
        #pragma unroll
        for (int c2 = 0; c2 < 2; ++c2) {
          int ct = ch*2 + c2;
          #pragma unroll
          for (int r = 0; r < 4; ++r)
            h[rt][ct][r] = __builtin_fmaf(0.5f, tanh_fast(acc[rt][c2][r]), 0.5f*h[rt][ct][r]);
        }
    }
    __syncthreads();
  }

  // ---- head: out = h @ head_w^T + head_b  (A split hi/lo, W single bf16) ----
  #pragma unroll
  for (int rt = 0; rt < 2; ++rt) {
    uint32_t rcomp = (uint32_t)(rt*16384);
    #pragma unroll
    for (int ct = 0; ct < 4; ++ct) {
      int c = wc*64 + ct*16 + l15;
      uint32_t wcomp = (uint32_t)(((c >> 5)*1024) + (((c >> 3) & 3)*256) + ((c & 7)*2) + ql*64);
      #pragma unroll
      for (int r = 0; r < 4; ++r) {
        float hv = h[rt][ct][r];
        short hi16 = f2bf(hv);
        uint32_t byte = axor(rcomp + wcomp + (uint32_t)(r*16));
        *(short*)(ldsHi + byte) = hi16;
        *(short*)(ldsLo + byte) = f2bf(hv - bf2f(hi16));
      }
    }
  }
  __syncthreads();

  int oc[2]; float hbv[2];
  #pragma unroll
  for (int c2 = 0; c2 < 2; ++c2) { oc[c2] = wc*32 + c2*16 + l15; hbv[c2] = headb[oc[c2]]; }
  f32x4 o[2][2];
  #pragma unroll
  for (int rt = 0; rt < 2; ++rt)
    #pragma unroll
    for (int c2 = 0; c2 < 2; ++c2) {
      f32x4 z; z[0]=hbv[c2]; z[1]=hbv[c2]; z[2]=hbv[c2]; z[3]=hbv[c2];
      o[rt][c2] = z;
    }
  {
    const char* pHd = (const char*)packHd + (size_t)wc*2048 + (size_t)lane*16;
    #pragma unroll 2
    for (int kt = 0; kt < 16; ++kt) {
      #pragma unroll
      for (int rt = 0; rt < 2; ++rt) {
        uint32_t byte = axor((uint32_t)((rt*16 + kt)*1024 + lane*16));
        short8 ah = *(const short8*)(ldsHi + byte);
        short8 al = *(const short8*)(ldsLo + byte);
        #pragma unroll
        for (int c2 = 0; c2 < 2; ++c2) {
          short8 b = *(const short8*)(pHd + c2*1024);
          o[rt][c2] = MFMA16(ah, b, o[rt][c2]);
          o[rt][c2] = MFMA16(al, b, o[rt][c2]);
        }
      }
      pHd += 16384;
    }
  }
  const size_t rowg = (size_t)rb*BROWS;
  #pragma unroll
  for (int rt = 0; rt < 2; ++rt)
    #pragma unroll
    for (int c2 = 0; c2 < 2; ++c2)
      #pragma unroll
      for (int r = 0; r < 4; ++r) {
        size_t row = rowg + rt*16 + ql*4 + r;
        out[row*OUTD + oc[c2]] = o[rt][c2][r];
      }
}

extern "C" void kernel_launch(void* const* d_in, const int* in_sizes, int n_in,
                              void* d_out, int out_size, void* d_ws, size_t ws_size,
                              hipStream_t stream)
{
  const float* x    = (const float*)d_in[0];
  const float* winw = (const float*)d_in[1];
  const float* winb = (const float*)d_in[2];
  const float* lw   = (const float*)d_in[3];
  const float* lb   = (const float*)d_in[4];
  const float* lu   = (const float*)d_in[5];
  const float* ow   = (const float*)d_in[6];
  const float* ou   = (const float*)d_in[7];
  const float* hw   = (const float*)d_in[8];
  const float* hb   = (const float*)d_in[9];
  const int*   st   = (const int*)d_in[10];
  float* out = (float*)d_out;
  char*  ws  = (char*)d_ws;

  float* invs   = (float*)(ws);
  float* bsum   = (float*)(ws + 1024);
  float* cs     = (float*)(ws + 4096);
  float* cn     = (float*)(ws + 8192);
  short* packWC = (short*)(ws + 16384);                    // 1 MiB (interleaved hi/lo)
  short* packIC = (short*)(ws + 16384 + 1048576);          // 512 KiB (interleaved hi/lo)
  short* packHd = (short*)(ws + 16384 + 1048576 + 524288); // 256 KiB (hi only)

  sigma_kernel<<<4, 512, 0, stream>>>(lw, lu, ow, ou, invs);
  pack_wsum_il<<<1024, 256, 0, stream>>>(lw, invs, packWC);
  pack_b_il<256, 512><<<512, 256, 0, stream>>>(winw, packIC);
  pack_b_hi<512, 256><<<512, 256, 0, stream>>>(hw, packHd);
  pack_small<<<2, 256, 0, stream>>>(lb, ow, invs, bsum, cs, cn);

  fused_main<<<65536/BROWS, 512, 0, stream>>>(x, winb, hb, st,
                                              packWC, packIC, packHd,
                                              bsum, cs, cn, out);
}

// Round 11
// 3101.030 us; speedup vs baseline: 1.4472x; 1.0107x over previous
//
#include <hip/hip_runtime.h>
#include <stdint.h>

#define HID 512
#define IND 256
#define OUTD 256
#define BROWS 32

typedef __attribute__((ext_vector_type(8))) short short8;   // 8 bf16 (4 VGPRs)
typedef __attribute__((ext_vector_type(4))) short short4v;  // 4 bf16
typedef __attribute__((ext_vector_type(4))) float f32x4;
typedef __attribute__((ext_vector_type(4))) int   i32x4;

#define MFMA16(a,b,c) __builtin_amdgcn_mfma_f32_16x16x32_bf16(a,b,c,0,0,0)

__device__ __forceinline__ short f2bf(float f){
  uint32_t u = __builtin_bit_cast(uint32_t, f);
  u += 0x7FFFu + ((u>>16)&1u);
  return (short)(u>>16);
}
__device__ __forceinline__ float bf2f(short s){
  uint32_t u = ((uint32_t)(uint16_t)s) << 16;
  return __builtin_bit_cast(float, u);
}
// pack one f32 as (hi bf16 | lo bf16) in one u32; unpack = hi + lo
__device__ __forceinline__ int pack_hl(float v){
  short hi = f2bf(v);
  short lo = f2bf(v - bf2f(hi));
  return (((int)(uint16_t)hi) << 16) | (int)(uint16_t)lo;
}
__device__ __forceinline__ float unpk(int p){
  float vh = __builtin_bit_cast(float, (uint32_t)p & 0xFFFF0000u);
  float vl = __builtin_bit_cast(float, (uint32_t)p << 16);
  return vh + vl;
}
__device__ __forceinline__ float tanh_fast(float x){
  float e = __builtin_amdgcn_exp2f(x * 2.88539008177792681472f);
  return __builtin_fmaf(-2.0f, __builtin_amdgcn_rcpf(e + 1.0f), 1.0f);
}
__device__ __forceinline__ float neigh(float v){
  // lane^1 exchange via DPP quad_perm [1,0,3,2]
  return __builtin_bit_cast(float,
      __builtin_amdgcn_mov_dpp(__builtin_bit_cast(int, v), 0xB1, 0xF, 0xF, true));
}
__device__ __forceinline__ uint32_t axor(uint32_t b){ return b ^ (((b>>7)&7u)<<4); }

// ---------------- sigma: one power-iteration step, one block per matrix ----------------
__global__ void sigma_kernel(const float* __restrict__ lw, const float* __restrict__ lu,
                             const float* __restrict__ ow, const float* __restrict__ ou,
                             float* __restrict__ invs)
{
  __shared__ float sv[HID];
  __shared__ float red[8];
  const int g = threadIdx.x;  // 512 threads
  const int m = blockIdx.x;   // 0..3
  const float* W = (m < 3) ? (lw + (size_t)m*HID*HID) : ow;
  const float* u = (m < 3) ? (lu + m*HID) : ou;
  float t1 = 0.f;
  for (int k = 0; k < HID; ++k) t1 += W[(size_t)k*HID + g] * u[k];
  float ss = t1*t1;
  #pragma unroll
  for (int d = 32; d; d >>= 1) ss += __shfl_xor(ss, d);
  if ((g & 63) == 0) red[g >> 6] = ss;
  __syncthreads();
  float tot = 0.f;
  #pragma unroll
  for (int i = 0; i < 8; ++i) tot += red[i];
  float nrm = sqrtf(tot);
  sv[g] = t1 / (nrm + 1e-12f);
  __syncthreads();
  float n = 0.f;
  const float* Wr = W + (size_t)g*HID;
  for (int k = 0; k < HID; ++k) n += Wr[k] * sv[k];
  float ss2 = n*n;
  #pragma unroll
  for (int d = 32; d; d >>= 1) ss2 += __shfl_xor(ss2, d);
  if ((g & 63) == 0) red[g >> 6] = ss2;
  __syncthreads();
  float tot2 = 0.f;
  #pragma unroll
  for (int i = 0; i < 8; ++i) tot2 += red[i];
  float nn = sqrtf(tot2);
  float sigma = tot2 / (nn + 1e-12f);   // dot(u2, Wv)
  if (g == 0) invs[m] = 1.0f / sigma;
}

// ---------------- weight packing: INTERLEAVED hi/lo, MFMA-frag-sequential ----------------
// Frag f = kt*NCT + ctg occupies 2 KiB: [0,1K) hi halves, [1K,2K) lo halves.
// B-frag mapping: lane l holds B[k = kt*32 + (l>>4)*8 + j][col = ctg*16 + (l&15)].
__global__ void pack_wsum_il(const float* __restrict__ lw, const float* __restrict__ invs,
                             short* __restrict__ pw)
{
  int i = blockIdx.x*blockDim.x + threadIdx.x;   // < 512*512
  int j = i & 7, lane = (i >> 3) & 63, f = i >> 9;
  int kt = f >> 5, ctg = f & 31;                 // NCT = 32
  int k = kt*32 + (lane >> 4)*8 + j;
  int g = ctg*16 + (lane & 15);
  size_t idx = (size_t)g*HID + k;
  float v = lw[idx]*invs[0] + lw[262144 + idx]*invs[1] + lw[524288 + idx]*invs[2];
  short hi = f2bf(v);
  pw[(size_t)f*1024 + lane*8 + j]       = hi;
  pw[(size_t)f*1024 + 512 + lane*8 + j] = f2bf(v - bf2f(hi));
}

template<int K, int N>
__global__ void pack_b_il(const float* __restrict__ W, short* __restrict__ pc)
{
  int i = blockIdx.x*blockDim.x + threadIdx.x;   // < K*N
  int j = i & 7, lane = (i >> 3) & 63, f = i >> 9;
  constexpr int NCT = N/16;
  int kt = f / NCT, ctg = f % NCT;
  int k = kt*32 + (lane >> 4)*8 + j;
  int c = ctg*16 + (lane & 15);
  float v = W[(size_t)c*K + k];
  short hi = f2bf(v);
  pc[(size_t)f*1024 + lane*8 + j]       = hi;
  pc[(size_t)f*1024 + 512 + lane*8 + j] = f2bf(v - bf2f(hi));
}

template<int K, int N>
__global__ void pack_b_hi(const float* __restrict__ W, short* __restrict__ pb)
{
  int i = blockIdx.x*blockDim.x + threadIdx.x;   // < K*N
  int j = i & 7, lane = (i >> 3) & 63, f = i >> 9;
  constexpr int NCT = N/16;
  int kt = f / NCT, ctg = f % NCT;
  int k = kt*32 + (lane >> 4)*8 + j;
  int c = ctg*16 + (lane & 15);
  pb[i] = f2bf(W[(size_t)c*K + k]);
}

__global__ void pack_small(const float* __restrict__ lb, const float* __restrict__ ow,
                           const float* __restrict__ invs,
                           float* __restrict__ bsum, float* __restrict__ cs, float* __restrict__ cn)
{
  int g = blockIdx.x*blockDim.x + threadIdx.x;
  if (g >= HID) return;
  bsum[g] = lb[g] + lb[HID + g] + lb[2*HID + g];
  float is = invs[3];
  cs[g] = ow[(size_t)g*HID + g] * is;        // osc_sn[g][g]
  cn[g] = ow[(size_t)g*HID + (g^1)] * is;    // osc_sn[g][g^1]
}

// ---------------- fused main: 32 rows, 512 threads (8 waves), wave tile 32x64 ----------------
// Target: 2 blocks/CU (4 waves/SIMD) so independent blocks overlap VALU/barrier
// phases with each other's MFMA. That requires TOTAL (arch+accum) regs <= 128/wave:
//   arch:  h32 + xp32 + frags ~24 + addr ~20  ~= 108
//   accum: <=16 at ALL times  (x_emb now done in ct-halves like the main loop;
//          R10's xe[2][4] 32-accum phase pushed the total past 128 and silently
//          kept us at 1 block/CU)
// LDS 64 KiB static (A hi/lo) -> 2 blocks fit in 160 KiB.
__global__ void __launch_bounds__(512) fused_main(
    const float* __restrict__ x,
    const float* __restrict__ winb,
    const float* __restrict__ headb,
    const int*  __restrict__ stepsp,
    const short* __restrict__ packWC,   // Wsum interleaved hi/lo, 1 MiB
    const short* __restrict__ packIC,   // W_in interleaved hi/lo, 512 KiB
    const short* __restrict__ packHd,   // head hi only, 256 KiB
    const float* __restrict__ bsumA,
    const float* __restrict__ csA,
    const float* __restrict__ cnA,
    float* __restrict__ out)
{
  __shared__ char ldsbuf[65536];
  char* ldsHi = ldsbuf;             // 32 KiB A_hi (frag-major, 32 frags x 1 KiB)
  char* ldsLo = ldsbuf + 32768;     // 32 KiB A_lo
  const int tid  = threadIdx.x;
  const int lane = tid & 63;
  const int l15  = lane & 15;
  const int ql   = lane >> 4;       // 0..3
  const int wid  = tid >> 6;        // 0..7
  const int wc   = wid;             // col group: 64 cols; every wave covers rows 0..31
  const int rb   = blockIdx.x;

  // ---- stage x tile -> LDS bf16 hi/lo, frag-major [rtg 0..1][kt 0..7] ----
  {
    const float* xb = x + (size_t)rb*BROWS*IND;
    #pragma unroll
    for (int i = 0; i < 4; ++i) {
      int fi  = i*512 + tid;        // 2048 float4s
      int row = fi >> 6;            // 0..31
      int c   = (fi & 63)*4;        // 0..252
      f32x4 v = *(const f32x4*)(xb + (size_t)row*IND + c);
      short4v hi4, lo4;
      #pragma unroll
      for (int j = 0; j < 4; ++j) {
        short h16 = f2bf(v[j]);
        hi4[j] = h16;
        lo4[j] = f2bf(v[j] - bf2f(h16));
      }
      int rtg = row >> 4, kt = c >> 5, qd = (c >> 3) & 3;
      uint32_t byte = (uint32_t)(((rtg*8 + kt)*1024) + (qd*16 + (row & 15))*16 + (c & 7)*2);
      *(short4v*)(ldsHi + axor(byte)) = hi4;
      *(short4v*)(ldsLo + axor(byte)) = lo4;
    }
  }
  __syncthreads();

  const int nsteps = stepsp[0];

  // Oscillator: uniform 2x2 rotation blocks -> one (cs, cn) pair per lane.
  const float cs_s = csA[wc*64 + l15];
  const float cn_s = cnA[wc*64 + l15];

  // ---- x_emb = x @ W_in^T + W_in_b + b_sum, in ct-HALVES (peak accum = 16) ----
  f32x4 h[2][4];
  i32x4 xp[2][4];     // packed hi|lo xe, arch-resident, fully static indexing
  #pragma unroll
  for (int ch = 0; ch < 2; ++ch) {
    f32x4 acc[2][2];
    #pragma unroll
    for (int c2 = 0; c2 < 2; ++c2) {
      int c = wc*64 + (ch*2 + c2)*16 + l15;
      float s = winb[c] + bsumA[c];
      #pragma unroll
      for (int rt = 0; rt < 2; ++rt) {
        f32x4 z; z[0]=s; z[1]=s; z[2]=s; z[3]=s;
        acc[rt][c2] = z;
      }
    }
    {
      const char* pI = (const char*)packIC + (size_t)wc*8192 + (size_t)(ch*4096) + (size_t)lane*16;
      __builtin_amdgcn_s_setprio(1);
      for (int kt = 0; kt < 8; ++kt) {
        short8 bh0 = *(const short8*)(pI);
        short8 bl0 = *(const short8*)(pI + 1024);
        short8 bh1 = *(const short8*)(pI + 2048);
        short8 bl1 = *(const short8*)(pI + 3072);
        #pragma unroll
        for (int rt = 0; rt < 2; ++rt) {
          uint32_t byte = axor((uint32_t)((rt*8 + kt)*1024 + lane*16));
          short8 ah = *(const short8*)(ldsHi + byte);
          short8 al = *(const short8*)(ldsLo + byte);
          acc[rt][0] = MFMA16(ah, bh0, acc[rt][0]);
          acc[rt][0] = MFMA16(al, bh0, acc[rt][0]);
          acc[rt][0] = MFMA16(ah, bl0, acc[rt][0]);
          acc[rt][1] = MFMA16(ah, bh1, acc[rt][1]);
          acc[rt][1] = MFMA16(al, bh1, acc[rt][1]);
          acc[rt][1] = MFMA16(ah, bl1, acc[rt][1]);
        }
        pI += 65536;
      }
      __builtin_amdgcn_s_setprio(0);
    }
    #pragma unroll
    for (int rt = 0; rt < 2; ++rt)
      #pragma unroll
      for (int c2 = 0; c2 < 2; ++c2) {
        int ct = ch*2 + c2;
        #pragma unroll
        for (int r = 0; r < 4; ++r) {
          float xv = acc[rt][c2][r];
          xp[rt][ct][r] = pack_hl(xv);
          h[rt][ct][r] = (nsteps >= 1) ? 0.5f * tanh_fast(xv) : 0.f;
        }
      }
  }
  __syncthreads();

  const char* baseW = (const char*)packWC + (size_t)wc*8192 + (size_t)lane*16;

  // ---- recurrence steps 2..nsteps ----
  for (int s = 1; s < nsteps; ++s) {
    // t = tanh(h) -> LDS hi/lo A-tiles (32 rows x 512 k, frag (rt*16+kt))
    #pragma unroll
    for (int rt = 0; rt < 2; ++rt) {
      uint32_t rcomp = (uint32_t)(rt*16384);
      #pragma unroll
      for (int ct = 0; ct < 4; ++ct) {
        int c = wc*64 + ct*16 + l15;
        uint32_t wcomp = (uint32_t)(((c >> 5)*1024) + (((c >> 3) & 3)*256) + ((c & 7)*2) + ql*64);
        #pragma unroll
        for (int r = 0; r < 4; ++r) {
          float t = tanh_fast(h[rt][ct][r]);
          short hi16 = f2bf(t);
          uint32_t byte = axor(rcomp + wcomp + (uint32_t)(r*16));
          *(short*)(ldsHi + byte) = hi16;
          *(short*)(ldsLo + byte) = f2bf(t - bf2f(hi16));
        }
      }
    }
    __syncthreads();

    #pragma unroll
    for (int ch = 0; ch < 2; ++ch) {      // ct-halves: acc 16 regs live
      f32x4 acc[2][2];
      #pragma unroll
      for (int rt = 0; rt < 2; ++rt)
        #pragma unroll
        for (int c2 = 0; c2 < 2; ++c2) {
          int ct = ch*2 + c2;
          #pragma unroll
          for (int r = 0; r < 4; ++r) {
            float hv = h[rt][ct][r];
            acc[rt][c2][r] = __builtin_fmaf(cs_s, hv,
                               __builtin_fmaf(cn_s, neigh(hv), unpk(xp[rt][ct][r])));
          }
        }
      const char* p = baseW + ch*4096;
      __builtin_amdgcn_s_setprio(1);
      #pragma unroll 2
      for (int kt = 0; kt < 16; ++kt) {
        short8 bh0 = *(const short8*)(p);
        short8 bl0 = *(const short8*)(p + 1024);
        short8 bh1 = *(const short8*)(p + 2048);
        short8 bl1 = *(const short8*)(p + 3072);
        #pragma unroll
        for (int rt = 0; rt < 2; ++rt) {
          uint32_t byte = axor((uint32_t)((rt*16 + kt)*1024 + lane*16));
          short8 ah = *(const short8*)(ldsHi + byte);
          short8 al = *(const short8*)(ldsLo + byte);
          acc[rt][0] = MFMA16(ah, bh0, acc[rt][0]);
          acc[rt][0] = MFMA16(al, bh0, acc[rt][0]);
          acc[rt][0] = MFMA16(ah, bl0, acc[rt][0]);
          acc[rt][1] = MFMA16(ah, bh1, acc[rt][1]);
          acc[rt][1] = MFMA16(al, bh1, acc[rt][1]);
          acc[rt][1] = MFMA16(ah, bl1, acc[rt][1]);
        }
        p += 65536;
      }
      __builtin_amdgcn_s_setprio(0);
      #pragma unroll
      for (int rt = 0; rt < 2; ++rt)
        #pragma unroll
        for (int c2 = 0; c2 < 2; ++c2) {
          int ct = ch*2 + c2;
          #pragma unroll
          for (int r = 0; r < 4; ++r)
            h[rt][ct][r] = __builtin_fmaf(0.5f, tanh_fast(acc[rt][c2][r]), 0.5f*h[rt][ct][r]);
        }
    }
    __syncthreads();
  }

  // ---- head: out = h @ head_w^T + head_b  (A split hi/lo, W single bf16) ----
  #pragma unroll
  for (int rt = 0; rt < 2; ++rt) {
    uint32_t rcomp = (uint32_t)(rt*16384);
    #pragma unroll
    for (int ct = 0; ct < 4; ++ct) {
      int c = wc*64 + ct*16 + l15;
      uint32_t wcomp = (uint32_t)(((c >> 5)*1024) + (((c >> 3) & 3)*256) + ((c & 7)*2) + ql*64);
      #pragma unroll
      for (int r = 0; r < 4; ++r) {
        float hv = h[rt][ct][r];
        short hi16 = f2bf(hv);
        uint32_t byte = axor(rcomp + wcomp + (uint32_t)(r*16));
        *(short*)(ldsHi + byte) = hi16;
        *(short*)(ldsLo + byte) = f2bf(hv - bf2f(hi16));
      }
    }
  }
  __syncthreads();

  int oc[2]; float hbv[2];
  #pragma unroll
  for (int c2 = 0; c2 < 2; ++c2) { oc[c2] = wc*32 + c2*16 + l15; hbv[c2] = headb[oc[c2]]; }
  f32x4 o[2][2];
  #pragma unroll
  for (int rt = 0; rt < 2; ++rt)
    #pragma unroll
    for (int c2 = 0; c2 < 2; ++c2) {
      f32x4 z; z[0]=hbv[c2]; z[1]=hbv[c2]; z[2]=hbv[c2]; z[3]=hbv[c2];
      o[rt][c2] = z;
    }
  {
    const char* pHd = (const char*)packHd + (size_t)wc*2048 + (size_t)lane*16;
    #pragma unroll 2
    for (int kt = 0; kt < 16; ++kt) {
      #pragma unroll
      for (int rt = 0; rt < 2; ++rt) {
        uint32_t byte = axor((uint32_t)((rt*16 + kt)*1024 + lane*16));
        short8 ah = *(const short8*)(ldsHi + byte);
        short8 al = *(const short8*)(ldsLo + byte);
        #pragma unroll
        for (int c2 = 0; c2 < 2; ++c2) {
          short8 b = *(const short8*)(pHd + c2*1024);
          o[rt][c2] = MFMA16(ah, b, o[rt][c2]);
          o[rt][c2] = MFMA16(al, b, o[rt][c2]);
        }
      }
      pHd += 16384;
    }
  }
  const size_t rowg = (size_t)rb*BROWS;
  #pragma unroll
  for (int rt = 0; rt < 2; ++rt)
    #pragma unroll
    for (int c2 = 0; c2 < 2; ++c2)
      #pragma unroll
      for (int r = 0; r < 4; ++r) {
        size_t row = rowg + rt*16 + ql*4 + r;
        out[row*OUTD + oc[c2]] = o[rt][c2][r];
      }
}

extern "C" void kernel_launch(void* const* d_in, const int* in_sizes, int n_in,
                              void* d_out, int out_size, void* d_ws, size_t ws_size,
                              hipStream_t stream)
{
  const float* x    = (const float*)d_in[0];
  const float* winw = (const float*)d_in[1];
  const float* winb = (const float*)d_in[2];
  const float* lw   = (const float*)d_in[3];
  const float* lb   = (const float*)d_in[4];
  const float* lu   = (const float*)d_in[5];
  const float* ow   = (const float*)d_in[6];
  const float* ou   = (const float*)d_in[7];
  const float* hw   = (const float*)d_in[8];
  const float* hb   = (const float*)d_in[9];
  const int*   st   = (const int*)d_in[10];
  float* out = (float*)d_out;
  char*  ws  = (char*)d_ws;

  float* invs   = (float*)(ws);
  float* bsum   = (float*)(ws + 1024);
  float* cs     = (float*)(ws + 4096);
  float* cn     = (float*)(ws + 8192);
  short* packWC = (short*)(ws + 16384);                    // 1 MiB (interleaved hi/lo)
  short* packIC = (short*)(ws + 16384 + 1048576);          // 512 KiB (interleaved hi/lo)
  short* packHd = (short*)(ws + 16384 + 1048576 + 524288); // 256 KiB (hi only)

  sigma_kernel<<<4, 512, 0, stream>>>(lw, lu, ow, ou, invs);
  pack_wsum_il<<<1024, 256, 0, stream>>>(lw, invs, packWC);
  pack_b_il<256, 512><<<512, 256, 0, stream>>>(winw, packIC);
  pack_b_hi<512, 256><<<512, 256, 0, stream>>>(hw, packHd);
  pack_small<<<2, 256, 0, stream>>>(lb, ow, invs, bsum, cs, cn);

  fused_main<<<65536/BROWS, 512, 0, stream>>>(x, winb, hb, st,
                                              packWC, packIC, packHd,
                                              bsum, cs, cn, out);
}

// Round 12
// 2340.819 us; speedup vs baseline: 1.9172x; 1.3248x over previous
//
#include <hip/hip_runtime.h>
#include <stdint.h>

#define HID 512
#define IND 256
#define OUTD 256
#define BROWS 32

typedef __attribute__((ext_vector_type(8))) short    short8;
typedef __attribute__((ext_vector_type(8))) _Float16 half8;   // 8 fp16 (4 VGPRs)
typedef __attribute__((ext_vector_type(4))) short    short4v;
typedef __attribute__((ext_vector_type(4))) float    f32x4;
typedef __attribute__((ext_vector_type(4))) int      i32x4;

#define MFMAH(a,b,c) __builtin_amdgcn_mfma_f32_16x16x32_f16(a,b,c,0,0,0)

__device__ __forceinline__ short f2bf(float f){
  uint32_t u = __builtin_bit_cast(uint32_t, f);
  u += 0x7FFFu + ((u>>16)&1u);
  return (short)(u>>16);
}
__device__ __forceinline__ float bf2f(short s){
  uint32_t u = ((uint32_t)(uint16_t)s) << 16;
  return __builtin_bit_cast(float, u);
}
__device__ __forceinline__ short f2h(float f){
  _Float16 h = (_Float16)f;
  return __builtin_bit_cast(short, h);
}
__device__ __forceinline__ float h2f(short s){
  return (float)__builtin_bit_cast(_Float16, s);
}
// xe packed as (hi bf16 | lo bf16) in one u32 — 2^-16 rel precision
__device__ __forceinline__ int pack_hl(float v){
  short hi = f2bf(v);
  short lo = f2bf(v - bf2f(hi));
  return (((int)(uint16_t)hi) << 16) | (int)(uint16_t)lo;
}
__device__ __forceinline__ float unpk(int p){
  float vh = __builtin_bit_cast(float, (uint32_t)p & 0xFFFF0000u);
  float vl = __builtin_bit_cast(float, (uint32_t)p << 16);
  return vh + vl;
}
__device__ __forceinline__ float tanh_fast(float x){
  float e = __builtin_amdgcn_exp2f(x * 2.88539008177792681472f);
  return __builtin_fmaf(-2.0f, __builtin_amdgcn_rcpf(e + 1.0f), 1.0f);
}
__device__ __forceinline__ float neigh(float v){
  return __builtin_bit_cast(float,
      __builtin_amdgcn_mov_dpp(__builtin_bit_cast(int, v), 0xB1, 0xF, 0xF, true));
}
__device__ __forceinline__ uint32_t axor(uint32_t b){ return b ^ (((b>>7)&7u)<<4); }

// ---------------- sigma ----------------
__global__ void sigma_kernel(const float* __restrict__ lw, const float* __restrict__ lu,
                             const float* __restrict__ ow, const float* __restrict__ ou,
                             float* __restrict__ invs)
{
  __shared__ float sv[HID];
  __shared__ float red[8];
  const int g = threadIdx.x;
  const int m = blockIdx.x;
  const float* W = (m < 3) ? (lw + (size_t)m*HID*HID) : ow;
  const float* u = (m < 3) ? (lu + m*HID) : ou;
  float t1 = 0.f;
  for (int k = 0; k < HID; ++k) t1 += W[(size_t)k*HID + g] * u[k];
  float ss = t1*t1;
  #pragma unroll
  for (int d = 32; d; d >>= 1) ss += __shfl_xor(ss, d);
  if ((g & 63) == 0) red[g >> 6] = ss;
  __syncthreads();
  float tot = 0.f;
  #pragma unroll
  for (int i = 0; i < 8; ++i) tot += red[i];
  float nrm = sqrtf(tot);
  sv[g] = t1 / (nrm + 1e-12f);
  __syncthreads();
  float n = 0.f;
  const float* Wr = W + (size_t)g*HID;
  for (int k = 0; k < HID; ++k) n += Wr[k] * sv[k];
  float ss2 = n*n;
  #pragma unroll
  for (int d = 32; d; d >>= 1) ss2 += __shfl_xor(ss2, d);
  if ((g & 63) == 0) red[g >> 6] = ss2;
  __syncthreads();
  float tot2 = 0.f;
  #pragma unroll
  for (int i = 0; i < 8; ++i) tot2 += red[i];
  float nn = sqrtf(tot2);
  float sigma = tot2 / (nn + 1e-12f);
  if (g == 0) invs[m] = 1.0f / sigma;
}

// ---------------- weight packing: SINGLE fp16, frag-sequential 1 KiB frags ----------------
// Frag f = kt*NCT + ctg: element (lane*8 + j); lane l holds
// B[k = kt*32 + (l>>4)*8 + j][col = ctg*16 + (l&15)].
__global__ void pack_wsum_f16(const float* __restrict__ lw, const float* __restrict__ invs,
                              short* __restrict__ pw)
{
  int i = blockIdx.x*blockDim.x + threadIdx.x;   // < 512*512
  int j = i & 7, lane = (i >> 3) & 63, f = i >> 9;
  int kt = f >> 5, ctg = f & 31;                 // NCT = 32
  int k = kt*32 + (lane >> 4)*8 + j;
  int g = ctg*16 + (lane & 15);
  size_t idx = (size_t)g*HID + k;
  float v = lw[idx]*invs[0] + lw[262144 + idx]*invs[1] + lw[524288 + idx]*invs[2];
  pw[i] = f2h(v);
}

template<int K, int N>
__global__ void pack_b_f16(const float* __restrict__ W, short* __restrict__ pb)
{
  int i = blockIdx.x*blockDim.x + threadIdx.x;   // < K*N
  int j = i & 7, lane = (i >> 3) & 63, f = i >> 9;
  constexpr int NCT = N/16;
  int kt = f / NCT, ctg = f % NCT;
  int k = kt*32 + (lane >> 4)*8 + j;
  int c = ctg*16 + (lane & 15);
  pb[i] = f2h(W[(size_t)c*K + k]);
}

__global__ void pack_small(const float* __restrict__ lb, const float* __restrict__ ow,
                           const float* __restrict__ invs,
                           float* __restrict__ bsum, float* __restrict__ cs, float* __restrict__ cn)
{
  int g = blockIdx.x*blockDim.x + threadIdx.x;
  if (g >= HID) return;
  bsum[g] = lb[g] + lb[HID + g] + lb[2*HID + g];
  float is = invs[3];
  cs[g] = ow[(size_t)g*HID + g] * is;
  cn[g] = ow[(size_t)g*HID + (g^1)] * is;
}

// ---------------- fused main: 32 rows, 512 threads (8 waves), wave tile 32x64 ----------------
// fp16 2-pass: A (tanh h) split hi/lo fp16 (exact to 2^-22); W single fp16 (2^-11).
// Per kt: 2 weight frag loads (1 KB each), 4 LDS A reads, 8 MFMA — vs bf16 3-pass's
// 4 loads / 4 reads / 12 MFMA. W L2 traffic and MFMA work both cut.
// LDS reads use ONE laneRd register + compile-time offsets (XOR mask proven
// lane-only: frag base is a multiple of 1024, lane*16 < 1024).
__global__ void __launch_bounds__(512) fused_main(
    const float* __restrict__ x,
    const float* __restrict__ winb,
    const float* __restrict__ headb,
    const int*  __restrict__ stepsp,
    const short* __restrict__ packW,    // Wsum fp16, 512 KiB
    const short* __restrict__ packI,    // W_in fp16, 256 KiB
    const short* __restrict__ packHd,   // head fp16, 256 KiB
    const float* __restrict__ bsumA,
    const float* __restrict__ csA,
    const float* __restrict__ cnA,
    float* __restrict__ out)
{
  __shared__ char ldsbuf[65536];
  char* ldsHi = ldsbuf;             // 32 KiB A_hi (frag-major, 32 frags x 1 KiB)
  char* ldsLo = ldsbuf + 32768;     // 32 KiB A_lo
  const int tid  = threadIdx.x;
  const int lane = tid & 63;
  const int l15  = lane & 15;
  const int ql   = lane >> 4;
  const int wc   = tid >> 6;        // 0..7, col group of 64
  const int rb   = blockIdx.x;

  const uint32_t laneRd = (uint32_t)((lane*16) ^ (((lane>>3)&7)<<4));

  // ---- stage x tile -> LDS fp16 hi/lo, frag-major [rtg 0..1][kt 0..7] ----
  {
    const float* xb = x + (size_t)rb*BROWS*IND;
    #pragma unroll
    for (int i = 0; i < 4; ++i) {
      int fi  = i*512 + tid;        // 2048 float4s
      int row = fi >> 6;
      int c   = (fi & 63)*4;
      f32x4 v = *(const f32x4*)(xb + (size_t)row*IND + c);
      short4v hi4, lo4;
      #pragma unroll
      for (int j = 0; j < 4; ++j) {
        short hh = f2h(v[j]);
        hi4[j] = hh;
        lo4[j] = f2h(v[j] - h2f(hh));
      }
      int rtg = row >> 4, kt = c >> 5, qd = (c >> 3) & 3;
      uint32_t byte = (uint32_t)(((rtg*8 + kt)*1024) + (qd*16 + (row & 15))*16 + (c & 7)*2);
      *(short4v*)(ldsHi + axor(byte)) = hi4;
      *(short4v*)(ldsLo + axor(byte)) = lo4;
    }
  }
  __syncthreads();

  const int nsteps = stepsp[0];

  const float cs_s = csA[wc*64 + l15];
  const float cn_s = cnA[wc*64 + l15];

  // ---- x_emb in ct-halves (peak accum = 16), fp16 2-pass ----
  f32x4 h[2][4];
  i32x4 xp[2][4];
  #pragma unroll
  for (int ch = 0; ch < 2; ++ch) {
    f32x4 acc[2][2];
    #pragma unroll
    for (int c2 = 0; c2 < 2; ++c2) {
      int c = wc*64 + (ch*2 + c2)*16 + l15;
      float s = winb[c] + bsumA[c];
      #pragma unroll
      for (int rt = 0; rt < 2; ++rt) {
        f32x4 z; z[0]=s; z[1]=s; z[2]=s; z[3]=s;
        acc[rt][c2] = z;
      }
    }
    {
      const char* pI = (const char*)packI + (size_t)wc*4096 + (size_t)(ch*2048) + (size_t)lane*16;
      __builtin_amdgcn_s_setprio(1);
      #pragma unroll 2
      for (int kt = 0; kt < 8; ++kt) {
        half8 b0 = *(const half8*)(pI);
        half8 b1 = *(const half8*)(pI + 1024);
        #pragma unroll
        for (int rt = 0; rt < 2; ++rt) {
          half8 ah = *(const half8*)(ldsHi + laneRd + (rt*8 + kt)*1024);
          half8 al = *(const half8*)(ldsLo + laneRd + (rt*8 + kt)*1024);
          acc[rt][0] = MFMAH(ah, b0, acc[rt][0]);
          acc[rt][0] = MFMAH(al, b0, acc[rt][0]);
          acc[rt][1] = MFMAH(ah, b1, acc[rt][1]);
          acc[rt][1] = MFMAH(al, b1, acc[rt][1]);
        }
        pI += 32768;
      }
      __builtin_amdgcn_s_setprio(0);
    }
    #pragma unroll
    for (int rt = 0; rt < 2; ++rt)
      #pragma unroll
      for (int c2 = 0; c2 < 2; ++c2) {
        int ct = ch*2 + c2;
        #pragma unroll
        for (int r = 0; r < 4; ++r) {
          float xv = acc[rt][c2][r];
          xp[rt][ct][r] = pack_hl(xv);
          h[rt][ct][r] = (nsteps >= 1) ? 0.5f * tanh_fast(xv) : 0.f;
        }
      }
  }
  __syncthreads();

  const char* baseW = (const char*)packW + (size_t)wc*4096 + (size_t)lane*16;

  // ---- recurrence steps 2..nsteps ----
  for (int s = 1; s < nsteps; ++s) {
    // t = tanh(h) -> LDS hi/lo fp16 A-tiles (frag (rt*16 + kt))
    #pragma unroll
    for (int rt = 0; rt < 2; ++rt) {
      uint32_t rcomp = (uint32_t)(rt*16384);
      #pragma unroll
      for (int ct = 0; ct < 4; ++ct) {
        int c = wc*64 + ct*16 + l15;
        uint32_t wcomp = (uint32_t)(((c >> 5)*1024) + (((c >> 3) & 3)*256) + ((c & 7)*2) + ql*64);
        #pragma unroll
        for (int r = 0; r < 4; ++r) {
          float t = tanh_fast(h[rt][ct][r]);
          short hh = f2h(t);
          uint32_t byte = axor(rcomp + wcomp + (uint32_t)(r*16));
          *(short*)(ldsHi + byte) = hh;
          *(short*)(ldsLo + byte) = f2h(t - h2f(hh));
        }
      }
    }
    __syncthreads();

    #pragma unroll
    for (int ch = 0; ch < 2; ++ch) {
      f32x4 acc[2][2];
      #pragma unroll
      for (int rt = 0; rt < 2; ++rt)
        #pragma unroll
        for (int c2 = 0; c2 < 2; ++c2) {
          int ct = ch*2 + c2;
          #pragma unroll
          for (int r = 0; r < 4; ++r) {
            float hv = h[rt][ct][r];
            acc[rt][c2][r] = __builtin_fmaf(cs_s, hv,
                               __builtin_fmaf(cn_s, neigh(hv), unpk(xp[rt][ct][r])));
          }
        }
      const char* p = baseW + ch*2048;
      __builtin_amdgcn_s_setprio(1);
      #pragma unroll 2
      for (int kt = 0; kt < 16; ++kt) {
        half8 b0 = *(const half8*)(p);
        half8 b1 = *(const half8*)(p + 1024);
        #pragma unroll
        for (int rt = 0; rt < 2; ++rt) {
          half8 ah = *(const half8*)(ldsHi + laneRd + (rt*16 + kt)*1024);
          half8 al = *(const half8*)(ldsLo + laneRd + (rt*16 + kt)*1024);
          acc[rt][0] = MFMAH(ah, b0, acc[rt][0]);
          acc[rt][0] = MFMAH(al, b0, acc[rt][0]);
          acc[rt][1] = MFMAH(ah, b1, acc[rt][1]);
          acc[rt][1] = MFMAH(al, b1, acc[rt][1]);
        }
        p += 32768;
      }
      __builtin_amdgcn_s_setprio(0);
      #pragma unroll
      for (int rt = 0; rt < 2; ++rt)
        #pragma unroll
        for (int c2 = 0; c2 < 2; ++c2) {
          int ct = ch*2 + c2;
          #pragma unroll
          for (int r = 0; r < 4; ++r)
            h[rt][ct][r] = __builtin_fmaf(0.5f, tanh_fast(acc[rt][c2][r]), 0.5f*h[rt][ct][r]);
        }
    }
    __syncthreads();
  }

  // ---- head: out = h @ head_w^T + head_b (h split hi/lo fp16, W single fp16) ----
  #pragma unroll
  for (int rt = 0; rt < 2; ++rt) {
    uint32_t rcomp = (uint32_t)(rt*16384);
    #pragma unroll
    for (int ct = 0; ct < 4; ++ct) {
      int c = wc*64 + ct*16 + l15;
      uint32_t wcomp = (uint32_t)(((c >> 5)*1024) + (((c >> 3) & 3)*256) + ((c & 7)*2) + ql*64);
      #pragma unroll
      for (int r = 0; r < 4; ++r) {
        float hv = h[rt][ct][r];
        short hh = f2h(hv);
        uint32_t byte = axor(rcomp + wcomp + (uint32_t)(r*16));
        *(short*)(ldsHi + byte) = hh;
        *(short*)(ldsLo + byte) = f2h(hv - h2f(hh));
      }
    }
  }
  __syncthreads();

  int oc[2]; float hbv[2];
  #pragma unroll
  for (int c2 = 0; c2 < 2; ++c2) { oc[c2] = wc*32 + c2*16 + l15; hbv[c2] = headb[oc[c2]]; }
  f32x4 o[2][2];
  #pragma unroll
  for (int rt = 0; rt < 2; ++rt)
    #pragma unroll
    for (int c2 = 0; c2 < 2; ++c2) {
      f32x4 z; z[0]=hbv[c2]; z[1]=hbv[c2]; z[2]=hbv[c2]; z[3]=hbv[c2];
      o[rt][c2] = z;
    }
  {
    const char* pHd = (const char*)packHd + (size_t)wc*2048 + (size_t)lane*16;
    #pragma unroll 2
    for (int kt = 0; kt < 16; ++kt) {
      #pragma unroll
      for (int rt = 0; rt < 2; ++rt) {
        half8 ah = *(const half8*)(ldsHi + laneRd + (rt*16 + kt)*1024);
        half8 al = *(const half8*)(ldsLo + laneRd + (rt*16 + kt)*1024);
        #pragma unroll
        for (int c2 = 0; c2 < 2; ++c2) {
          half8 b = *(const half8*)(pHd + c2*1024);
          o[rt][c2] = MFMAH(ah, b, o[rt][c2]);
          o[rt][c2] = MFMAH(al, b, o[rt][c2]);
        }
      }
      pHd += 16384;
    }
  }
  const size_t rowg = (size_t)rb*BROWS;
  #pragma unroll
  for (int rt = 0; rt < 2; ++rt)
    #pragma unroll
    for (int c2 = 0; c2 < 2; ++c2)
      #pragma unroll
      for (int r = 0; r < 4; ++r) {
        size_t row = rowg + rt*16 + ql*4 + r;
        out[row*OUTD + oc[c2]] = o[rt][c2][r];
      }
}

extern "C" void kernel_launch(void* const* d_in, const int* in_sizes, int n_in,
                              void* d_out, int out_size, void* d_ws, size_t ws_size,
                              hipStream_t stream)
{
  const float* x    = (const float*)d_in[0];
  const float* winw = (const float*)d_in[1];
  const float* winb = (const float*)d_in[2];
  const float* lw   = (const float*)d_in[3];
  const float* lb   = (const float*)d_in[4];
  const float* lu   = (const float*)d_in[5];
  const float* ow   = (const float*)d_in[6];
  const float* ou   = (const float*)d_in[7];
  const float* hw   = (const float*)d_in[8];
  const float* hb   = (const float*)d_in[9];
  const int*   st   = (const int*)d_in[10];
  float* out = (float*)d_out;
  char*  ws  = (char*)d_ws;

  float* invs   = (float*)(ws);
  float* bsum   = (float*)(ws + 1024);
  float* cs     = (float*)(ws + 4096);
  float* cn     = (float*)(ws + 8192);
  short* packW  = (short*)(ws + 16384);                    // 512 KiB fp16
  short* packI  = (short*)(ws + 16384 + 524288);           // 256 KiB fp16
  short* packHd = (short*)(ws + 16384 + 524288 + 262144);  // 256 KiB fp16

  sigma_kernel<<<4, 512, 0, stream>>>(lw, lu, ow, ou, invs);
  pack_wsum_f16<<<1024, 256, 0, stream>>>(lw, invs, packW);
  pack_b_f16<256, 512><<<512, 256, 0, stream>>>(winw, packI);
  pack_b_f16<512, 256><<<512, 256, 0, stream>>>(hw, packHd);
  pack_small<<<2, 256, 0, stream>>>(lb, ow, invs, bsum, cs, cn);

  fused_main<<<65536/BROWS, 512, 0, stream>>>(x, winb, hb, st,
                                              packW, packI, packHd,
                                              bsum, cs, cn, out);
}

// Round 13
// 2199.178 us; speedup vs baseline: 2.0406x; 1.0644x over previous
//
#include <hip/hip_runtime.h>
#include <stdint.h>

#define HID 512
#define IND 256
#define OUTD 256
#define BROWS 32

typedef __attribute__((ext_vector_type(8))) short    short8;
typedef __attribute__((ext_vector_type(8))) _Float16 half8;   // 8 fp16 (4 VGPRs)
typedef __attribute__((ext_vector_type(4))) short    short4v;
typedef __attribute__((ext_vector_type(4))) float    f32x4;
typedef __attribute__((ext_vector_type(4))) int      i32x4;

#define MFMAH(a,b,c) __builtin_amdgcn_mfma_f32_16x16x32_f16(a,b,c,0,0,0)

__device__ __forceinline__ short f2bf(float f){
  uint32_t u = __builtin_bit_cast(uint32_t, f);
  u += 0x7FFFu + ((u>>16)&1u);
  return (short)(u>>16);
}
__device__ __forceinline__ float bf2f(short s){
  uint32_t u = ((uint32_t)(uint16_t)s) << 16;
  return __builtin_bit_cast(float, u);
}
__device__ __forceinline__ short f2h(float f){
  _Float16 h = (_Float16)f;
  return __builtin_bit_cast(short, h);
}
__device__ __forceinline__ float h2f(short s){
  return (float)__builtin_bit_cast(_Float16, s);
}
// xe packed as (hi bf16 | lo bf16) in one u32 — 2^-16 rel precision
__device__ __forceinline__ int pack_hl(float v){
  short hi = f2bf(v);
  short lo = f2bf(v - bf2f(hi));
  return (((int)(uint16_t)hi) << 16) | (int)(uint16_t)lo;
}
__device__ __forceinline__ float unpk(int p){
  float vh = __builtin_bit_cast(float, (uint32_t)p & 0xFFFF0000u);
  float vl = __builtin_bit_cast(float, (uint32_t)p << 16);
  return vh + vl;
}
__device__ __forceinline__ float tanh_fast(float x){
  float e = __builtin_amdgcn_exp2f(x * 2.88539008177792681472f);
  return __builtin_fmaf(-2.0f, __builtin_amdgcn_rcpf(e + 1.0f), 1.0f);
}
__device__ __forceinline__ float neigh(float v){
  return __builtin_bit_cast(float,
      __builtin_amdgcn_mov_dpp(__builtin_bit_cast(int, v), 0xB1, 0xF, 0xF, true));
}
__device__ __forceinline__ uint32_t axor(uint32_t b){ return b ^ (((b>>7)&7u)<<4); }

// ---------------- sigma ----------------
__global__ void sigma_kernel(const float* __restrict__ lw, const float* __restrict__ lu,
                             const float* __restrict__ ow, const float* __restrict__ ou,
                             float* __restrict__ invs)
{
  __shared__ float sv[HID];
  __shared__ float red[8];
  const int g = threadIdx.x;
  const int m = blockIdx.x;
  const float* W = (m < 3) ? (lw + (size_t)m*HID*HID) : ow;
  const float* u = (m < 3) ? (lu + m*HID) : ou;
  float t1 = 0.f;
  for (int k = 0; k < HID; ++k) t1 += W[(size_t)k*HID + g] * u[k];
  float ss = t1*t1;
  #pragma unroll
  for (int d = 32; d; d >>= 1) ss += __shfl_xor(ss, d);
  if ((g & 63) == 0) red[g >> 6] = ss;
  __syncthreads();
  float tot = 0.f;
  #pragma unroll
  for (int i = 0; i < 8; ++i) tot += red[i];
  float nrm = sqrtf(tot);
  sv[g] = t1 / (nrm + 1e-12f);
  __syncthreads();
  float n = 0.f;
  const float* Wr = W + (size_t)g*HID;
  for (int k = 0; k < HID; ++k) n += Wr[k] * sv[k];
  float ss2 = n*n;
  #pragma unroll
  for (int d = 32; d; d >>= 1) ss2 += __shfl_xor(ss2, d);
  if ((g & 63) == 0) red[g >> 6] = ss2;
  __syncthreads();
  float tot2 = 0.f;
  #pragma unroll
  for (int i = 0; i < 8; ++i) tot2 += red[i];
  float nn = sqrtf(tot2);
  float sigma = tot2 / (nn + 1e-12f);
  if (g == 0) invs[m] = 1.0f / sigma;
}

// ---------------- weight packing: SINGLE fp16, frag-sequential 1 KiB frags ----------------
// Frag f = kt*NCT + ctg: element (lane*8 + j); lane l holds
// B[k = kt*32 + (l>>4)*8 + j][col = ctg*16 + (l&15)].
__global__ void pack_wsum_f16(const float* __restrict__ lw, const float* __restrict__ invs,
                              short* __restrict__ pw)
{
  int i = blockIdx.x*blockDim.x + threadIdx.x;   // < 512*512
  int j = i & 7, lane = (i >> 3) & 63, f = i >> 9;
  int kt = f >> 5, ctg = f & 31;                 // NCT = 32
  int k = kt*32 + (lane >> 4)*8 + j;
  int g = ctg*16 + (lane & 15);
  size_t idx = (size_t)g*HID + k;
  float v = lw[idx]*invs[0] + lw[262144 + idx]*invs[1] + lw[524288 + idx]*invs[2];
  pw[i] = f2h(v);
}

template<int K, int N>
__global__ void pack_b_f16(const float* __restrict__ W, short* __restrict__ pb)
{
  int i = blockIdx.x*blockDim.x + threadIdx.x;   // < K*N
  int j = i & 7, lane = (i >> 3) & 63, f = i >> 9;
  constexpr int NCT = N/16;
  int kt = f / NCT, ctg = f % NCT;
  int k = kt*32 + (lane >> 4)*8 + j;
  int c = ctg*16 + (lane & 15);
  pb[i] = f2h(W[(size_t)c*K + k]);
}

__global__ void pack_small(const float* __restrict__ lb, const float* __restrict__ ow,
                           const float* __restrict__ invs,
                           float* __restrict__ bsum, float* __restrict__ cs, float* __restrict__ cn)
{
  int g = blockIdx.x*blockDim.x + threadIdx.x;
  if (g >= HID) return;
  bsum[g] = lb[g] + lb[HID + g] + lb[2*HID + g];
  float is = invs[3];
  cs[g] = ow[(size_t)g*HID + g] * is;
  cn[g] = ow[(size_t)g*HID + (g^1)] * is;
}

// ---------------- fused main: 32 rows, 512 threads (8 waves), wave tile 32x64 ----------------
// fp16 2-pass (A split hi/lo, W single fp16), SINGLE merged kt loop:
// acc[2][4] (32 accum), 4 B-frags/kt, A-frags read ONCE per kt (R12's ch-halves
// read every A-frag twice — LDS reads were the largest cycle component).
// Budget at 8 waves/CU (2/SIMD, 256 regs): arch ~116 + accum 32 — ample.
__global__ void __launch_bounds__(512) fused_main(
    const float* __restrict__ x,
    const float* __restrict__ winb,
    const float* __restrict__ headb,
    const int*  __restrict__ stepsp,
    const short* __restrict__ packW,    // Wsum fp16, 512 KiB
    const short* __restrict__ packI,    // W_in fp16, 256 KiB
    const short* __restrict__ packHd,   // head fp16, 256 KiB
    const float* __restrict__ bsumA,
    const float* __restrict__ csA,
    const float* __restrict__ cnA,
    float* __restrict__ out)
{
  __shared__ char ldsbuf[65536];
  char* ldsHi = ldsbuf;             // 32 KiB A_hi (frag-major, 32 frags x 1 KiB)
  char* ldsLo = ldsbuf + 32768;     // 32 KiB A_lo
  const int tid  = threadIdx.x;
  const int lane = tid & 63;
  const int l15  = lane & 15;
  const int ql   = lane >> 4;
  const int wc   = tid >> 6;        // 0..7, col group of 64
  const int rb   = blockIdx.x;

  const uint32_t laneRd = (uint32_t)((lane*16) ^ (((lane>>3)&7)<<4));

  // ---- stage x tile -> LDS fp16 hi/lo, frag-major [rtg 0..1][kt 0..7] ----
  {
    const float* xb = x + (size_t)rb*BROWS*IND;
    #pragma unroll
    for (int i = 0; i < 4; ++i) {
      int fi  = i*512 + tid;        // 2048 float4s
      int row = fi >> 6;
      int c   = (fi & 63)*4;
      f32x4 v = *(const f32x4*)(xb + (size_t)row*IND + c);
      short4v hi4, lo4;
      #pragma unroll
      for (int j = 0; j < 4; ++j) {
        short hh = f2h(v[j]);
        hi4[j] = hh;
        lo4[j] = f2h(v[j] - h2f(hh));
      }
      int rtg = row >> 4, kt = c >> 5, qd = (c >> 3) & 3;
      uint32_t byte = (uint32_t)(((rtg*8 + kt)*1024) + (qd*16 + (row & 15))*16 + (c & 7)*2);
      *(short4v*)(ldsHi + axor(byte)) = hi4;
      *(short4v*)(ldsLo + axor(byte)) = lo4;
    }
  }
  __syncthreads();

  const int nsteps = stepsp[0];

  const float cs_s = csA[wc*64 + l15];
  const float cn_s = cnA[wc*64 + l15];

  // ---- x_emb: single merged loop, acc[2][4], fp16 2-pass ----
  f32x4 h[2][4];
  i32x4 xp[2][4];
  {
    f32x4 acc[2][4];
    #pragma unroll
    for (int ct = 0; ct < 4; ++ct) {
      int c = wc*64 + ct*16 + l15;
      float s = winb[c] + bsumA[c];
      #pragma unroll
      for (int rt = 0; rt < 2; ++rt) {
        f32x4 z; z[0]=s; z[1]=s; z[2]=s; z[3]=s;
        acc[rt][ct] = z;
      }
    }
    {
      const char* pI = (const char*)packI + (size_t)wc*4096 + (size_t)lane*16;
      __builtin_amdgcn_s_setprio(1);
      #pragma unroll 2
      for (int kt = 0; kt < 8; ++kt) {
        half8 b0 = *(const half8*)(pI);
        half8 b1 = *(const half8*)(pI + 1024);
        half8 b2 = *(const half8*)(pI + 2048);
        half8 b3 = *(const half8*)(pI + 3072);
        #pragma unroll
        for (int rt = 0; rt < 2; ++rt) {
          half8 ah = *(const half8*)(ldsHi + laneRd + (rt*8 + kt)*1024);
          half8 al = *(const half8*)(ldsLo + laneRd + (rt*8 + kt)*1024);
          acc[rt][0] = MFMAH(ah, b0, acc[rt][0]);
          acc[rt][0] = MFMAH(al, b0, acc[rt][0]);
          acc[rt][1] = MFMAH(ah, b1, acc[rt][1]);
          acc[rt][1] = MFMAH(al, b1, acc[rt][1]);
          acc[rt][2] = MFMAH(ah, b2, acc[rt][2]);
          acc[rt][2] = MFMAH(al, b2, acc[rt][2]);
          acc[rt][3] = MFMAH(ah, b3, acc[rt][3]);
          acc[rt][3] = MFMAH(al, b3, acc[rt][3]);
        }
        pI += 32768;
      }
      __builtin_amdgcn_s_setprio(0);
    }
    #pragma unroll
    for (int rt = 0; rt < 2; ++rt)
      #pragma unroll
      for (int ct = 0; ct < 4; ++ct)
        #pragma unroll
        for (int r = 0; r < 4; ++r) {
          float xv = acc[rt][ct][r];
          xp[rt][ct][r] = pack_hl(xv);
          h[rt][ct][r] = (nsteps >= 1) ? 0.5f * tanh_fast(xv) : 0.f;
        }
  }
  __syncthreads();

  const char* baseW = (const char*)packW + (size_t)wc*4096 + (size_t)lane*16;

  // ---- recurrence steps 2..nsteps ----
  for (int s = 1; s < nsteps; ++s) {
    // t = tanh(h) -> LDS hi/lo fp16 A-tiles (frag (rt*16 + kt))
    #pragma unroll
    for (int rt = 0; rt < 2; ++rt) {
      uint32_t rcomp = (uint32_t)(rt*16384);
      #pragma unroll
      for (int ct = 0; ct < 4; ++ct) {
        int c = wc*64 + ct*16 + l15;
        uint32_t wcomp = (uint32_t)(((c >> 5)*1024) + (((c >> 3) & 3)*256) + ((c & 7)*2) + ql*64);
        #pragma unroll
        for (int r = 0; r < 4; ++r) {
          float t = tanh_fast(h[rt][ct][r]);
          short hh = f2h(t);
          uint32_t byte = axor(rcomp + wcomp + (uint32_t)(r*16));
          *(short*)(ldsHi + byte) = hh;
          *(short*)(ldsLo + byte) = f2h(t - h2f(hh));
        }
      }
    }
    __syncthreads();

    f32x4 acc[2][4];
    #pragma unroll
    for (int rt = 0; rt < 2; ++rt)
      #pragma unroll
      for (int ct = 0; ct < 4; ++ct)
        #pragma unroll
        for (int r = 0; r < 4; ++r) {
          float hv = h[rt][ct][r];
          acc[rt][ct][r] = __builtin_fmaf(cs_s, hv,
                             __builtin_fmaf(cn_s, neigh(hv), unpk(xp[rt][ct][r])));
        }
    {
      const char* p = baseW;
      __builtin_amdgcn_s_setprio(1);
      #pragma unroll 2
      for (int kt = 0; kt < 16; ++kt) {
        half8 b0 = *(const half8*)(p);
        half8 b1 = *(const half8*)(p + 1024);
        half8 b2 = *(const half8*)(p + 2048);
        half8 b3 = *(const half8*)(p + 3072);
        #pragma unroll
        for (int rt = 0; rt < 2; ++rt) {
          half8 ah = *(const half8*)(ldsHi + laneRd + (rt*16 + kt)*1024);
          half8 al = *(const half8*)(ldsLo + laneRd + (rt*16 + kt)*1024);
          acc[rt][0] = MFMAH(ah, b0, acc[rt][0]);
          acc[rt][0] = MFMAH(al, b0, acc[rt][0]);
          acc[rt][1] = MFMAH(ah, b1, acc[rt][1]);
          acc[rt][1] = MFMAH(al, b1, acc[rt][1]);
          acc[rt][2] = MFMAH(ah, b2, acc[rt][2]);
          acc[rt][2] = MFMAH(al, b2, acc[rt][2]);
          acc[rt][3] = MFMAH(ah, b3, acc[rt][3]);
          acc[rt][3] = MFMAH(al, b3, acc[rt][3]);
        }
        p += 32768;
      }
      __builtin_amdgcn_s_setprio(0);
    }
    #pragma unroll
    for (int rt = 0; rt < 2; ++rt)
      #pragma unroll
      for (int ct = 0; ct < 4; ++ct)
        #pragma unroll
        for (int r = 0; r < 4; ++r)
          h[rt][ct][r] = __builtin_fmaf(0.5f, tanh_fast(acc[rt][ct][r]), 0.5f*h[rt][ct][r]);
    __syncthreads();
  }

  // ---- head: out = h @ head_w^T + head_b (h split hi/lo fp16, W single fp16) ----
  #pragma unroll
  for (int rt = 0; rt < 2; ++rt) {
    uint32_t rcomp = (uint32_t)(rt*16384);
    #pragma unroll
    for (int ct = 0; ct < 4; ++ct) {
      int c = wc*64 + ct*16 + l15;
      uint32_t wcomp = (uint32_t)(((c >> 5)*1024) + (((c >> 3) & 3)*256) + ((c & 7)*2) + ql*64);
      #pragma unroll
      for (int r = 0; r < 4; ++r) {
        float hv = h[rt][ct][r];
        short hh = f2h(hv);
        uint32_t byte = axor(rcomp + wcomp + (uint32_t)(r*16));
        *(short*)(ldsHi + byte) = hh;
        *(short*)(ldsLo + byte) = f2h(hv - h2f(hh));
      }
    }
  }
  __syncthreads();

  int oc[2]; float hbv[2];
  #pragma unroll
  for (int c2 = 0; c2 < 2; ++c2) { oc[c2] = wc*32 + c2*16 + l15; hbv[c2] = headb[oc[c2]]; }
  f32x4 o[2][2];
  #pragma unroll
  for (int rt = 0; rt < 2; ++rt)
    #pragma unroll
    for (int c2 = 0; c2 < 2; ++c2) {
      f32x4 z; z[0]=hbv[c2]; z[1]=hbv[c2]; z[2]=hbv[c2]; z[3]=hbv[c2];
      o[rt][c2] = z;
    }
  {
    const char* pHd = (const char*)packHd + (size_t)wc*2048 + (size_t)lane*16;
    #pragma unroll 2
    for (int kt = 0; kt < 16; ++kt) {
      #pragma unroll
      for (int rt = 0; rt < 2; ++rt) {
        half8 ah = *(const half8*)(ldsHi + laneRd + (rt*16 + kt)*1024);
        half8 al = *(const half8*)(ldsLo + laneRd + (rt*16 + kt)*1024);
        #pragma unroll
        for (int c2 = 0; c2 < 2; ++c2) {
          half8 b = *(const half8*)(pHd + c2*1024);
          o[rt][c2] = MFMAH(ah, b, o[rt][c2]);
          o[rt][c2] = MFMAH(al, b, o[rt][c2]);
        }
      }
      pHd += 16384;
    }
  }
  const size_t rowg = (size_t)rb*BROWS;
  #pragma unroll
  for (int rt = 0; rt < 2; ++rt)
    #pragma unroll
    for (int c2 = 0; c2 < 2; ++c2)
      #pragma unroll
      for (int r = 0; r < 4; ++r) {
        size_t row = rowg + rt*16 + ql*4 + r;
        out[row*OUTD + oc[c2]] = o[rt][c2][r];
      }
}

extern "C" void kernel_launch(void* const* d_in, const int* in_sizes, int n_in,
                              void* d_out, int out_size, void* d_ws, size_t ws_size,
                              hipStream_t stream)
{
  const float* x    = (const float*)d_in[0];
  const float* winw = (const float*)d_in[1];
  const float* winb = (const float*)d_in[2];
  const float* lw   = (const float*)d_in[3];
  const float* lb   = (const float*)d_in[4];
  const float* lu   = (const float*)d_in[5];
  const float* ow   = (const float*)d_in[6];
  const float* ou   = (const float*)d_in[7];
  const float* hw   = (const float*)d_in[8];
  const float* hb   = (const float*)d_in[9];
  const int*   st   = (const int*)d_in[10];
  float* out = (float*)d_out;
  char*  ws  = (char*)d_ws;

  float* invs   = (float*)(ws);
  float* bsum   = (float*)(ws + 1024);
  float* cs     = (float*)(ws + 4096);
  float* cn     = (float*)(ws + 8192);
  short* packW  = (short*)(ws + 16384);                    // 512 KiB fp16
  short* packI  = (short*)(ws + 16384 + 524288);           // 256 KiB fp16
  short* packHd = (short*)(ws + 16384 + 524288 + 262144);  // 256 KiB fp16

  sigma_kernel<<<4, 512, 0, stream>>>(lw, lu, ow, ou, invs);
  pack_wsum_f16<<<1024, 256, 0, stream>>>(lw, invs, packW);
  pack_b_f16<256, 512><<<512, 256, 0, stream>>>(winw, packI);
  pack_b_f16<512, 256><<<512, 256, 0, stream>>>(hw, packHd);
  pack_small<<<2, 256, 0, stream>>>(lb, ow, invs, bsum, cs, cn);

  fused_main<<<65536/BROWS, 512, 0, stream>>>(x, winb, hb, st,
                                              packW, packI, packHd,
                                              bsum, cs, cn, out);
}

// Round 14
// 1578.310 us; speedup vs baseline: 2.8434x; 1.3934x over previous
//
#include <hip/hip_runtime.h>
#include <stdint.h>

#define HID 512
#define IND 256
#define OUTD 256
#define BROWS 32

typedef __attribute__((ext_vector_type(8))) short    short8;
typedef __attribute__((ext_vector_type(8))) _Float16 half8;   // 8 fp16 (4 VGPRs)
typedef __attribute__((ext_vector_type(4))) short    short4v;
typedef __attribute__((ext_vector_type(4))) float    f32x4;
typedef __attribute__((ext_vector_type(4))) int      i32x4;

#define MFMAH(a,b,c) __builtin_amdgcn_mfma_f32_16x16x32_f16(a,b,c,0,0,0)

__device__ __forceinline__ short f2bf(float f){
  uint32_t u = __builtin_bit_cast(uint32_t, f);
  u += 0x7FFFu + ((u>>16)&1u);
  return (short)(u>>16);
}
__device__ __forceinline__ float bf2f(short s){
  uint32_t u = ((uint32_t)(uint16_t)s) << 16;
  return __builtin_bit_cast(float, u);
}
__device__ __forceinline__ short f2h(float f){
  _Float16 h = (_Float16)f;
  return __builtin_bit_cast(short, h);
}
__device__ __forceinline__ float h2f(short s){
  return (float)__builtin_bit_cast(_Float16, s);
}
// xe packed as (hi bf16 | lo bf16) in one u32 — 2^-16 rel precision
__device__ __forceinline__ int pack_hl(float v){
  short hi = f2bf(v);
  short lo = f2bf(v - bf2f(hi));
  return (((int)(uint16_t)hi) << 16) | (int)(uint16_t)lo;
}
__device__ __forceinline__ float unpk(int p){
  float vh = __builtin_bit_cast(float, (uint32_t)p & 0xFFFF0000u);
  float vl = __builtin_bit_cast(float, (uint32_t)p << 16);
  return vh + vl;
}
__device__ __forceinline__ float tanh_fast(float x){
  float e = __builtin_amdgcn_exp2f(x * 2.88539008177792681472f);
  return __builtin_fmaf(-2.0f, __builtin_amdgcn_rcpf(e + 1.0f), 1.0f);
}
__device__ __forceinline__ float neigh(float v){
  return __builtin_bit_cast(float,
      __builtin_amdgcn_mov_dpp(__builtin_bit_cast(int, v), 0xB1, 0xF, 0xF, true));
}
__device__ __forceinline__ uint32_t axor(uint32_t b){ return b ^ (((b>>7)&7u)<<4); }

// ---------------- sigma ----------------
__global__ void sigma_kernel(const float* __restrict__ lw, const float* __restrict__ lu,
                             const float* __restrict__ ow, const float* __restrict__ ou,
                             float* __restrict__ invs)
{
  __shared__ float sv[HID];
  __shared__ float red[8];
  const int g = threadIdx.x;
  const int m = blockIdx.x;
  const float* W = (m < 3) ? (lw + (size_t)m*HID*HID) : ow;
  const float* u = (m < 3) ? (lu + m*HID) : ou;
  float t1 = 0.f;
  for (int k = 0; k < HID; ++k) t1 += W[(size_t)k*HID + g] * u[k];
  float ss = t1*t1;
  #pragma unroll
  for (int d = 32; d; d >>= 1) ss += __shfl_xor(ss, d);
  if ((g & 63) == 0) red[g >> 6] = ss;
  __syncthreads();
  float tot = 0.f;
  #pragma unroll
  for (int i = 0; i < 8; ++i) tot += red[i];
  float nrm = sqrtf(tot);
  sv[g] = t1 / (nrm + 1e-12f);
  __syncthreads();
  float n = 0.f;
  const float* Wr = W + (size_t)g*HID;
  for (int k = 0; k < HID; ++k) n += Wr[k] * sv[k];
  float ss2 = n*n;
  #pragma unroll
  for (int d = 32; d; d >>= 1) ss2 += __shfl_xor(ss2, d);
  if ((g & 63) == 0) red[g >> 6] = ss2;
  __syncthreads();
  float tot2 = 0.f;
  #pragma unroll
  for (int i = 0; i < 8; ++i) tot2 += red[i];
  float nn = sqrtf(tot2);
  float sigma = tot2 / (nn + 1e-12f);
  if (g == 0) invs[m] = 1.0f / sigma;
}

// ---------------- weight packing: SINGLE fp16, frag-sequential 1 KiB frags ----------------
// Frag f = kt*NCT + ctg: element (lane*8 + j); lane l holds
// B[k = kt*32 + (l>>4)*8 + j][col = ctg*16 + (l&15)].
__global__ void pack_wsum_f16(const float* __restrict__ lw, const float* __restrict__ invs,
                              short* __restrict__ pw)
{
  int i = blockIdx.x*blockDim.x + threadIdx.x;   // < 512*512
  int j = i & 7, lane = (i >> 3) & 63, f = i >> 9;
  int kt = f >> 5, ctg = f & 31;                 // NCT = 32
  int k = kt*32 + (lane >> 4)*8 + j;
  int g = ctg*16 + (lane & 15);
  size_t idx = (size_t)g*HID + k;
  float v = lw[idx]*invs[0] + lw[262144 + idx]*invs[1] + lw[524288 + idx]*invs[2];
  pw[i] = f2h(v);
}

template<int K, int N>
__global__ void pack_b_f16(const float* __restrict__ W, short* __restrict__ pb)
{
  int i = blockIdx.x*blockDim.x + threadIdx.x;   // < K*N
  int j = i & 7, lane = (i >> 3) & 63, f = i >> 9;
  constexpr int NCT = N/16;
  int kt = f / NCT, ctg = f % NCT;
  int k = kt*32 + (lane >> 4)*8 + j;
  int c = ctg*16 + (lane & 15);
  pb[i] = f2h(W[(size_t)c*K + k]);
}

__global__ void pack_small(const float* __restrict__ lb, const float* __restrict__ ow,
                           const float* __restrict__ invs,
                           float* __restrict__ bsum, float* __restrict__ cs, float* __restrict__ cn)
{
  int g = blockIdx.x*blockDim.x + threadIdx.x;
  if (g >= HID) return;
  bsum[g] = lb[g] + lb[HID + g] + lb[2*HID + g];
  float is = invs[3];
  cs[g] = ow[(size_t)g*HID + g] * is;
  cn[g] = ow[(size_t)g*HID + (g^1)] * is;
}

// ---------------- fused main: 32 rows, 512 threads (8 waves), wave tile 32x64 ----------------
// Recurrence matmul: SINGLE-pass fp16 (t and W both fp16, rounding 2^-11 each).
// Justified empirically: absmax was bit-identical (0.015625) from R2's split-bf16
// 3-pass through R13's fp16 2-pass — the error floor is not matmul-precision-
// sourced. x_emb and head remain 2-pass (one-time cost, keeps xe/out exact).
// Per kt: 4 B loads, 2 A reads, 8 MFMA. tanh-store phase: hi plane only.
__global__ void __launch_bounds__(512) fused_main(
    const float* __restrict__ x,
    const float* __restrict__ winb,
    const float* __restrict__ headb,
    const int*  __restrict__ stepsp,
    const short* __restrict__ packW,    // Wsum fp16, 512 KiB
    const short* __restrict__ packI,    // W_in fp16, 256 KiB
    const short* __restrict__ packHd,   // head fp16, 256 KiB
    const float* __restrict__ bsumA,
    const float* __restrict__ csA,
    const float* __restrict__ cnA,
    float* __restrict__ out)
{
  __shared__ char ldsbuf[65536];
  char* ldsHi = ldsbuf;             // 32 KiB A_hi (frag-major, 32 frags x 1 KiB)
  char* ldsLo = ldsbuf + 32768;     // 32 KiB A_lo (x_emb + head phases only)
  const int tid  = threadIdx.x;
  const int lane = tid & 63;
  const int l15  = lane & 15;
  const int ql   = lane >> 4;
  const int wc   = tid >> 6;        // 0..7, col group of 64
  const int rb   = blockIdx.x;

  const uint32_t laneRd = (uint32_t)((lane*16) ^ (((lane>>3)&7)<<4));

  // ---- stage x tile -> LDS fp16 hi/lo, frag-major [rtg 0..1][kt 0..7] ----
  {
    const float* xb = x + (size_t)rb*BROWS*IND;
    #pragma unroll
    for (int i = 0; i < 4; ++i) {
      int fi  = i*512 + tid;        // 2048 float4s
      int row = fi >> 6;
      int c   = (fi & 63)*4;
      f32x4 v = *(const f32x4*)(xb + (size_t)row*IND + c);
      short4v hi4, lo4;
      #pragma unroll
      for (int j = 0; j < 4; ++j) {
        short hh = f2h(v[j]);
        hi4[j] = hh;
        lo4[j] = f2h(v[j] - h2f(hh));
      }
      int rtg = row >> 4, kt = c >> 5, qd = (c >> 3) & 3;
      uint32_t byte = (uint32_t)(((rtg*8 + kt)*1024) + (qd*16 + (row & 15))*16 + (c & 7)*2);
      *(short4v*)(ldsHi + axor(byte)) = hi4;
      *(short4v*)(ldsLo + axor(byte)) = lo4;
    }
  }
  __syncthreads();

  const int nsteps = stepsp[0];

  const float cs_s = csA[wc*64 + l15];
  const float cn_s = cnA[wc*64 + l15];

  // ---- x_emb: single merged loop, acc[2][4], fp16 2-pass (exact A) ----
  f32x4 h[2][4];
  i32x4 xp[2][4];
  {
    f32x4 acc[2][4];
    #pragma unroll
    for (int ct = 0; ct < 4; ++ct) {
      int c = wc*64 + ct*16 + l15;
      float s = winb[c] + bsumA[c];
      #pragma unroll
      for (int rt = 0; rt < 2; ++rt) {
        f32x4 z; z[0]=s; z[1]=s; z[2]=s; z[3]=s;
        acc[rt][ct] = z;
      }
    }
    {
      const char* pI = (const char*)packI + (size_t)wc*4096 + (size_t)lane*16;
      __builtin_amdgcn_s_setprio(1);
      #pragma unroll 2
      for (int kt = 0; kt < 8; ++kt) {
        half8 b0 = *(const half8*)(pI);
        half8 b1 = *(const half8*)(pI + 1024);
        half8 b2 = *(const half8*)(pI + 2048);
        half8 b3 = *(const half8*)(pI + 3072);
        #pragma unroll
        for (int rt = 0; rt < 2; ++rt) {
          half8 ah = *(const half8*)(ldsHi + laneRd + (rt*8 + kt)*1024);
          half8 al = *(const half8*)(ldsLo + laneRd + (rt*8 + kt)*1024);
          acc[rt][0] = MFMAH(ah, b0, acc[rt][0]);
          acc[rt][0] = MFMAH(al, b0, acc[rt][0]);
          acc[rt][1] = MFMAH(ah, b1, acc[rt][1]);
          acc[rt][1] = MFMAH(al, b1, acc[rt][1]);
          acc[rt][2] = MFMAH(ah, b2, acc[rt][2]);
          acc[rt][2] = MFMAH(al, b2, acc[rt][2]);
          acc[rt][3] = MFMAH(ah, b3, acc[rt][3]);
          acc[rt][3] = MFMAH(al, b3, acc[rt][3]);
        }
        pI += 32768;
      }
      __builtin_amdgcn_s_setprio(0);
    }
    #pragma unroll
    for (int rt = 0; rt < 2; ++rt)
      #pragma unroll
      for (int ct = 0; ct < 4; ++ct)
        #pragma unroll
        for (int r = 0; r < 4; ++r) {
          float xv = acc[rt][ct][r];
          xp[rt][ct][r] = pack_hl(xv);
          h[rt][ct][r] = (nsteps >= 1) ? 0.5f * tanh_fast(xv) : 0.f;
        }
  }
  __syncthreads();

  const char* baseW = (const char*)packW + (size_t)wc*4096 + (size_t)lane*16;

  // ---- recurrence steps 2..nsteps (single-pass fp16) ----
  for (int s = 1; s < nsteps; ++s) {
    // t = tanh(h) -> LDS hi-plane fp16 A-tiles (frag (rt*16 + kt))
    #pragma unroll
    for (int rt = 0; rt < 2; ++rt) {
      uint32_t rcomp = (uint32_t)(rt*16384);
      #pragma unroll
      for (int ct = 0; ct < 4; ++ct) {
        int c = wc*64 + ct*16 + l15;
        uint32_t wcomp = (uint32_t)(((c >> 5)*1024) + (((c >> 3) & 3)*256) + ((c & 7)*2) + ql*64);
        #pragma unroll
        for (int r = 0; r < 4; ++r) {
          float t = tanh_fast(h[rt][ct][r]);
          uint32_t byte = axor(rcomp + wcomp + (uint32_t)(r*16));
          *(short*)(ldsHi + byte) = f2h(t);
        }
      }
    }
    __syncthreads();

    f32x4 acc[2][4];
    #pragma unroll
    for (int rt = 0; rt < 2; ++rt)
      #pragma unroll
      for (int ct = 0; ct < 4; ++ct)
        #pragma unroll
        for (int r = 0; r < 4; ++r) {
          float hv = h[rt][ct][r];
          acc[rt][ct][r] = __builtin_fmaf(cs_s, hv,
                             __builtin_fmaf(cn_s, neigh(hv), unpk(xp[rt][ct][r])));
        }
    {
      const char* p = baseW;
      __builtin_amdgcn_s_setprio(1);
      #pragma unroll 4
      for (int kt = 0; kt < 16; ++kt) {
        half8 b0 = *(const half8*)(p);
        half8 b1 = *(const half8*)(p + 1024);
        half8 b2 = *(const half8*)(p + 2048);
        half8 b3 = *(const half8*)(p + 3072);
        #pragma unroll
        for (int rt = 0; rt < 2; ++rt) {
          half8 ah = *(const half8*)(ldsHi + laneRd + (rt*16 + kt)*1024);
          acc[rt][0] = MFMAH(ah, b0, acc[rt][0]);
          acc[rt][1] = MFMAH(ah, b1, acc[rt][1]);
          acc[rt][2] = MFMAH(ah, b2, acc[rt][2]);
          acc[rt][3] = MFMAH(ah, b3, acc[rt][3]);
        }
        p += 32768;
      }
      __builtin_amdgcn_s_setprio(0);
    }
    #pragma unroll
    for (int rt = 0; rt < 2; ++rt)
      #pragma unroll
      for (int ct = 0; ct < 4; ++ct)
        #pragma unroll
        for (int r = 0; r < 4; ++r)
          h[rt][ct][r] = __builtin_fmaf(0.5f, tanh_fast(acc[rt][ct][r]), 0.5f*h[rt][ct][r]);
    __syncthreads();
  }

  // ---- head: out = h @ head_w^T + head_b (h split hi/lo fp16, W single fp16) ----
  #pragma unroll
  for (int rt = 0; rt < 2; ++rt) {
    uint32_t rcomp = (uint32_t)(rt*16384);
    #pragma unroll
    for (int ct = 0; ct < 4; ++ct) {
      int c = wc*64 + ct*16 + l15;
      uint32_t wcomp = (uint32_t)(((c >> 5)*1024) + (((c >> 3) & 3)*256) + ((c & 7)*2) + ql*64);
      #pragma unroll
      for (int r = 0; r < 4; ++r) {
        float hv = h[rt][ct][r];
        short hh = f2h(hv);
        uint32_t byte = axor(rcomp + wcomp + (uint32_t)(r*16));
        *(short*)(ldsHi + byte) = hh;
        *(short*)(ldsLo + byte) = f2h(hv - h2f(hh));
      }
    }
  }
  __syncthreads();

  int oc[2]; float hbv[2];
  #pragma unroll
  for (int c2 = 0; c2 < 2; ++c2) { oc[c2] = wc*32 + c2*16 + l15; hbv[c2] = headb[oc[c2]]; }
  f32x4 o[2][2];
  #pragma unroll
  for (int rt = 0; rt < 2; ++rt)
    #pragma unroll
    for (int c2 = 0; c2 < 2; ++c2) {
      f32x4 z; z[0]=hbv[c2]; z[1]=hbv[c2]; z[2]=hbv[c2]; z[3]=hbv[c2];
      o[rt][c2] = z;
    }
  {
    const char* pHd = (const char*)packHd + (size_t)wc*2048 + (size_t)lane*16;
    #pragma unroll 2
    for (int kt = 0; kt < 16; ++kt) {
      #pragma unroll
      for (int rt = 0; rt < 2; ++rt) {
        half8 ah = *(const half8*)(ldsHi + laneRd + (rt*16 + kt)*1024);
        half8 al = *(const half8*)(ldsLo + laneRd + (rt*16 + kt)*1024);
        #pragma unroll
        for (int c2 = 0; c2 < 2; ++c2) {
          half8 b = *(const half8*)(pHd + c2*1024);
          o[rt][c2] = MFMAH(ah, b, o[rt][c2]);
          o[rt][c2] = MFMAH(al, b, o[rt][c2]);
        }
      }
      pHd += 16384;
    }
  }
  const size_t rowg = (size_t)rb*BROWS;
  #pragma unroll
  for (int rt = 0; rt < 2; ++rt)
    #pragma unroll
    for (int c2 = 0; c2 < 2; ++c2)
      #pragma unroll
      for (int r = 0; r < 4; ++r) {
        size_t row = rowg + rt*16 + ql*4 + r;
        out[row*OUTD + oc[c2]] = o[rt][c2][r];
      }
}

extern "C" void kernel_launch(void* const* d_in, const int* in_sizes, int n_in,
                              void* d_out, int out_size, void* d_ws, size_t ws_size,
                              hipStream_t stream)
{
  const float* x    = (const float*)d_in[0];
  const float* winw = (const float*)d_in[1];
  const float* winb = (const float*)d_in[2];
  const float* lw   = (const float*)d_in[3];
  const float* lb   = (const float*)d_in[4];
  const float* lu   = (const float*)d_in[5];
  const float* ow   = (const float*)d_in[6];
  const float* ou   = (const float*)d_in[7];
  const float* hw   = (const float*)d_in[8];
  const float* hb   = (const float*)d_in[9];
  const int*   st   = (const int*)d_in[10];
  float* out = (float*)d_out;
  char*  ws  = (char*)d_ws;

  float* invs   = (float*)(ws);
  float* bsum   = (float*)(ws + 1024);
  float* cs     = (float*)(ws + 4096);
  float* cn     = (float*)(ws + 8192);
  short* packW  = (short*)(ws + 16384);                    // 512 KiB fp16
  short* packI  = (short*)(ws + 16384 + 524288);           // 256 KiB fp16
  short* packHd = (short*)(ws + 16384 + 524288 + 262144);  // 256 KiB fp16

  sigma_kernel<<<4, 512, 0, stream>>>(lw, lu, ow, ou, invs);
  pack_wsum_f16<<<1024, 256, 0, stream>>>(lw, invs, packW);
  pack_b_f16<256, 512><<<512, 256, 0, stream>>>(winw, packI);
  pack_b_f16<512, 256><<<512, 256, 0, stream>>>(hw, packHd);
  pack_small<<<2, 256, 0, stream>>>(lb, ow, invs, bsum, cs, cn);

  fused_main<<<65536/BROWS, 512, 0, stream>>>(x, winb, hb, st,
                                              packW, packI, packHd,
                                              bsum, cs, cn, out);
}